// Round 2
// baseline (838.914 us; speedup 1.0000x reference)
//
#include <hip/hip_runtime.h>
#include <hip/hip_bf16.h>

#define L 1152
#define NRES 384
#define CS 256
#define CZ 128
#define H 8
#define CH 16
#define PQ 8
#define PV 12
#define PROJC 1056

// workspace offsets (in floats)
#define OFF_SLN  0L          // 1152*256      = 294912
#define OFF_PROJ 294912L     // 1152*1056     = 1216512
#define OFF_QG   1511424L    // 1152*192      = 221184
#define OFF_KT   1732608L    // 8*16*1152     = 147456
#define OFF_KGT  1880064L    // 8*24*1152     = 221184
#define OFF_VG   2101248L    // 1152*288      = 331776
#define OFF_BRES 2433024L    // 384*384*8     = 1179648
#define OFF_MURS 3612672L    // 384*384*2     = 294912
#define OFF_ATTN 3907584L    // 8*1152*1152   = 10616832
#define OFF_CAT  14524416L   // 1152*1536     = 1769472
// total fp32: 16293888 floats = 65.2 MB

// ---------------- kernel 1: LayerNorm(s) -> fp32 -------------------
__global__ __launch_bounds__(256) void k_ln_s(const float* s, const float* sc, const float* bi, float* sln){
  int l = blockIdx.x, t = threadIdx.x;
  __shared__ float red[CS];
  float x = s[(long)l*CS + t];
  red[t] = x; __syncthreads();
  for(int st=128; st>0; st>>=1){ if(t<st) red[t]+=red[t+st]; __syncthreads(); }
  float mu = red[0] * (1.f/CS); __syncthreads();
  float d = x - mu;
  red[t] = d*d; __syncthreads();
  for(int st=128; st>0; st>>=1){ if(t<st) red[t]+=red[t+st]; __syncthreads(); }
  float var = red[0]*(1.f/CS);
  sln[(long)l*CS + t] = d*rsqrtf(var + 1e-5f)*sc[t] + bi[t];
}

// ---------------- kernel 2: all six projections --------------------
__global__ __launch_bounds__(256) void k_proj(const float* sln, float* proj,
                       const float* wq, const float* wk, const float* wv,
                       const float* wqp, const float* wkp, const float* wvp){
  int l0 = blockIdx.x*4, t = threadIdx.x;
  __shared__ float sle[4][CS];
  for(int i=t;i<4*CS;i+=256) sle[i>>8][i&255] = sln[(long)(l0 + (i>>8))*CS + (i&255)];
  __syncthreads();
#define DO_PROJ(W, C, OFFC) \
  for(int c=t;c<(C);c+=256){ float a0=0,a1=0,a2=0,a3=0; \
    for(int k=0;k<CS;k++){ float w=W[(long)k*(C)+c]; \
      a0+=sle[0][k]*w; a1+=sle[1][k]*w; a2+=sle[2][k]*w; a3+=sle[3][k]*w;} \
    proj[(long)(l0+0)*PROJC+(OFFC)+c]=a0; proj[(long)(l0+1)*PROJC+(OFFC)+c]=a1; \
    proj[(long)(l0+2)*PROJC+(OFFC)+c]=a2; proj[(long)(l0+3)*PROJC+(OFFC)+c]=a3; }
  DO_PROJ(wq, 128, 0)
  DO_PROJ(wk, 128, 128)
  DO_PROJ(wv, 128, 256)
  DO_PROJ(wqp,192, 384)
  DO_PROJ(wkp,192, 576)
  DO_PROJ(wvp,288, 768)
#undef DO_PROJ
}

// ---------------- kernel 3: LayerNorm(z) stats + b_res = z_ln @ w_b
// 2 z-rows per 256-thread block; wave-shuffle reductions.
__global__ __launch_bounds__(256) void k_ln_z(const float* z, const float* sc, const float* bi,
                       const float* wb, float* murs, float* bres){
  long rpB = (long)blockIdx.x*2;
  int t = threadIdx.x;
  long rp = rpB + (t>>7);
  int c = t & 127;
  int w = t >> 6;          // wave id 0..3 (waves 0,1 -> row0; 2,3 -> row1)
  __shared__ float ls[4];
  __shared__ float lp[4][8];
  float x = z[rp*CZ + c];
  float s = x;
  #pragma unroll
  for(int off=32; off; off>>=1) s += __shfl_xor(s, off, 64);
  if((t & 63)==0) ls[w] = s;
  __syncthreads();
  float mu = (ls[w&2] + ls[(w&2)|1]) * (1.f/CZ);
  __syncthreads();
  float d = x - mu;
  s = d*d;
  #pragma unroll
  for(int off=32; off; off>>=1) s += __shfl_xor(s, off, 64);
  if((t & 63)==0) ls[w] = s;
  __syncthreads();
  float var = (ls[w&2] + ls[(w&2)|1]) * (1.f/CZ);
  float rstd = rsqrtf(var + 1e-5f);
  if(c==0){ murs[rp*2]=mu; murs[rp*2+1]=rstd; }
  float val = d*rstd*sc[c] + bi[c];
  float p[8];
  #pragma unroll
  for(int h=0;h<8;h++) p[h] = val * wb[(long)c*8 + h];
  #pragma unroll
  for(int off=32; off; off>>=1){
    #pragma unroll
    for(int h=0;h<8;h++) p[h] += __shfl_xor(p[h], off, 64);
  }
  if((t & 63)==0){
    #pragma unroll
    for(int h=0;h<8;h++) lp[w][h]=p[h];
  }
  __syncthreads();
  if(t < 16){
    int r=t>>3, h=t&7;
    bres[(rpB+r)*8 + h] = lp[r*2][h] + lp[r*2+1][h];
  }
}

// ---------------- kernel 4: rigid transforms -----------------------
// q_g[l][h*24+m], k_t[h*16+c][l], kg_t[h*24+m][l], v_g[l][h*36+m]
__global__ __launch_bounds__(256) void k_rigid(const float* proj, const float* rot, const float* trans,
                        float* qg, float* kt, float* kgt, float* vg){
  int l = blockIdx.x, t = threadIdx.x;
  __shared__ float R[9], T[3];
  if(t<9) R[t]=rot[(long)l*9+t];
  if(t<3) T[t]=trans[(long)l*3+t];
  __syncthreads();
  const float* pr = proj + (long)l*PROJC;
  if(t < 192){
    int h=t/24, m=t%24, p=m/3, i=m%3;
    {
      float a = R[i*3+0]*pr[384+h*24+p*3+0] + R[i*3+1]*pr[384+h*24+p*3+1]
              + R[i*3+2]*pr[384+h*24+p*3+2] + T[i];
      qg[(long)l*192+t]=a;
    }
    {
      float a = R[i*3+0]*pr[576+h*24+p*3+0] + R[i*3+1]*pr[576+h*24+p*3+1]
              + R[i*3+2]*pr[576+h*24+p*3+2] + T[i];
      kgt[(long)t*L + l]=a;
    }
  }
  if(t<128) kt[(long)t*L + l] = pr[128+t];
  for(int it=t; it<288; it+=256){
    int h=it/36, m=it%36, p=m/3, i=m%3;
    float a = R[i*3+0]*pr[768+h*36+p*3+0] + R[i*3+1]*pr[768+h*36+p*3+1]
            + R[i*3+2]*pr[768+h*36+p*3+2] + T[i];
    vg[(long)l*288+it]=a;
  }
}

// ---------------- kernel 5: attention scores + softmax -------------
__global__ __launch_bounds__(256) void k_scores(const float* proj, const float* qg, const float* kt,
                         const float* kgt, const float* bres, const int* ridx,
                         const float* mask, const float* hws, float* attn){
  int l = blockIdx.x, h = blockIdx.y, t = threadIdx.x;
  __shared__ float qls[CH], qgs[24], red[256];
  if(t<CH) qls[t]=proj[(long)l*PROJC + h*CH + t];
  if(t<24) qgs[t]=qg[(long)l*192 + h*24 + t];
  __syncthreads();
  float qq=0;
  #pragma unroll
  for(int m=0;m<24;m++) qq+=qgs[m]*qgs[m];
  float hw = log1pf(expf(hws[h]))*0.09622504486493764f;  // softplus * sqrt(1/108)
  int rl = ridx[l];
  float areg[5]; int cnt=0;
  float lmax=-1e30f;
  for(int j=t; j<L; j+=256){
    float dq=0;
    #pragma unroll
    for(int c=0;c<CH;c++) dq += qls[c]*kt[(long)(h*CH+c)*L + j];
    float kk=0, qkp=0;
    #pragma unroll
    for(int m=0;m<24;m++){ float kv = kgt[(long)(h*24+m)*L + j]; qkp+=qgs[m]*kv; kk+=kv*kv; }
    float bias = bres[((long)rl*NRES + ridx[j])*H + h];
    float a = dq*0.14433756729740643f + 0.5773502691896258f*bias
            - 0.5f*hw*(qq + kk - 2.f*qkp)
            + (mask[j]-1.f)*1e9f;
    areg[cnt++]=a;
    lmax = fmaxf(lmax, a);
  }
  red[t]=lmax; __syncthreads();
  for(int st=128;st>0;st>>=1){ if(t<st) red[t]=fmaxf(red[t],red[t+st]); __syncthreads(); }
  float amax = red[0]; __syncthreads();
  float lsum=0;
  for(int i=0;i<cnt;i++){ areg[i]=expf(areg[i]-amax); lsum+=areg[i]; }
  red[t]=lsum; __syncthreads();
  for(int st=128;st>0;st>>=1){ if(t<st) red[t]+=red[t+st]; __syncthreads(); }
  float inv = 1.f/red[0];
  float* arow = attn + ((long)h*L + l)*L;
  cnt=0;
  for(int j=t;j<L;j+=256) arow[j] = areg[cnt++]*inv;
}

// ---------------- kernel 6: o = attn@v, o_pt = rot^T(attn@v_g - t), norms
__global__ __launch_bounds__(256) void k_av(const float* attn, const float* proj, const float* vg,
                     const float* rot, const float* trans, float* cat){
  int l=blockIdx.x, h=blockIdx.y, t=threadIdx.x;
  __shared__ float as[L];
  __shared__ float red[256];
  __shared__ float fin[64];
  const float* arow = attn + ((long)h*L+l)*L;
  for(int j=t;j<L;j+=256) as[j]=arow[j];
  __syncthreads();
  int d=t&63, ch=t>>6;
  float acc=0;
  int j0=ch*288, j1=j0+288;
  if(d<16){
    for(int j=j0;j<j1;j++) acc += as[j]*proj[(long)j*PROJC + 256 + h*CH + d];
  } else if(d<52){
    int m=d-16;
    for(int j=j0;j<j1;j++) acc += as[j]*vg[(long)j*288 + h*36 + m];
  }
  red[t]=acc; __syncthreads();
  if(t<64) fin[t]=red[t]+red[t+64]+red[t+128]+red[t+192];
  __syncthreads();
  float* crow = cat + (long)l*1536 + h*192;
  if(t<16) crow[t]=fin[t];
  if(t>=16 && t<28){
    int p=t-16;
    float og[3];
    #pragma unroll
    for(int j=0;j<3;j++) og[j]=fin[16+p*3+j]-trans[(long)l*3+j];
    float nrm=0;
    #pragma unroll
    for(int i=0;i<3;i++){
      float v = rot[(long)l*9+0*3+i]*og[0]
              + rot[(long)l*9+1*3+i]*og[1]
              + rot[(long)l*9+2*3+i]*og[2];
      crow[16+p*3+i]=v; nrm+=v*v;
    }
    crow[52+p]=sqrtf(nrm+1e-8f);
  }
}

// ---------------- kernel 7: o_pair (z_ln recomputed on the fly) ----
__global__ __launch_bounds__(256) void k_opair(const float* attn, const float* z, const float* murs,
                        const float* sc, const float* bi, const int* ridx, float* cat){
  int l=blockIdx.x, t=threadIdx.x;
  __shared__ float ar[H][NRES];
  for(int it=t; it<H*NRES; it+=256){
    int h=it/NRES, n=it%NRES;
    const float* arow = attn + ((long)h*L+l)*L + n*3;
    ar[h][n]=arow[0]+arow[1]+arow[2];
  }
  __syncthreads();
  int c=t&127, hg=(t>>7)*4;
  int rl=ridx[l];
  float scc=sc[c], bic=bi[c];
  float acc0=0,acc1=0,acc2=0,acc3=0;
  const float* zrow = z + ((long)rl*NRES)*CZ + c;
  const float* mr = murs + (long)rl*NRES*2;
  for(int n=0;n<NRES;n++){
    float zv=(zrow[(long)n*CZ] - mr[n*2])*mr[n*2+1]*scc + bic;
    acc0+=ar[hg+0][n]*zv; acc1+=ar[hg+1][n]*zv;
    acc2+=ar[hg+2][n]*zv; acc3+=ar[hg+3][n]*zv;
  }
  float* crow = cat + (long)l*1536;
  crow[(hg+0)*192+64+c]=acc0; crow[(hg+1)*192+64+c]=acc1;
  crow[(hg+2)*192+64+c]=acc2; crow[(hg+3)*192+64+c]=acc3;
}

// ---------------- kernel 8: final GEMM + bias ----------------------
__global__ __launch_bounds__(256) void k_final(const float* cat, const float* wout, const float* bout, float* out){
  int l0=blockIdx.x*4, t=threadIdx.x;
  __shared__ float cs4[4][1536];
  for(int i=t;i<4*1536;i+=256) cs4[i/1536][i%1536]=cat[(long)(l0+i/1536)*1536 + (i%1536)];
  __syncthreads();
  float b0=bout[t];
  float a0=b0,a1=b0,a2=b0,a3=b0;
  for(int k=0;k<1536;k++){
    float w=wout[(long)k*CS+t];
    a0+=cs4[0][k]*w; a1+=cs4[1][k]*w; a2+=cs4[2][k]*w; a3+=cs4[3][k]*w;
  }
  out[(long)(l0+0)*CS+t]=a0;
  out[(long)(l0+1)*CS+t]=a1;
  out[(long)(l0+2)*CS+t]=a2;
  out[(long)(l0+3)*CS+t]=a3;
}

extern "C" void kernel_launch(void* const* d_in, const int* in_sizes, int n_in,
                              void* d_out, int out_size, void* d_ws, size_t ws_size,
                              hipStream_t stream) {
  const float* s      = (const float*)d_in[0];
  const float* z      = (const float*)d_in[1];
  const float* rot    = (const float*)d_in[2];
  const float* trans  = (const float*)d_in[3];
  const float* mask   = (const float*)d_in[4];
  const float* lnss   = (const float*)d_in[5];
  const float* lnsb   = (const float*)d_in[6];
  const float* lnzs   = (const float*)d_in[7];
  const float* lnzb   = (const float*)d_in[8];
  const float* wq     = (const float*)d_in[9];
  const float* wk     = (const float*)d_in[10];
  const float* wv     = (const float*)d_in[11];
  const float* wqp    = (const float*)d_in[12];
  const float* wkp    = (const float*)d_in[13];
  const float* wvp    = (const float*)d_in[14];
  const float* wb     = (const float*)d_in[15];
  const float* hws    = (const float*)d_in[16];
  const float* wout   = (const float*)d_in[17];
  const float* bout   = (const float*)d_in[18];
  const int*  ridx    = (const int*)d_in[19];

  float* ws  = (float*)d_ws;
  float* out = (float*)d_out;

  float* sln  = ws + OFF_SLN;
  float* proj = ws + OFF_PROJ;
  float* qg   = ws + OFF_QG;
  float* kt   = ws + OFF_KT;
  float* kgt  = ws + OFF_KGT;
  float* vg   = ws + OFF_VG;
  float* bres = ws + OFF_BRES;
  float* murs = ws + OFF_MURS;
  float* attn = ws + OFF_ATTN;
  float* cat  = ws + OFF_CAT;

  k_ln_s<<<dim3(L), dim3(CS), 0, stream>>>(s, lnss, lnsb, sln);
  k_proj<<<dim3(L/4), dim3(256), 0, stream>>>(sln, proj, wq, wk, wv, wqp, wkp, wvp);
  k_ln_z<<<dim3(NRES*NRES/2), dim3(256), 0, stream>>>(z, lnzs, lnzb, wb, murs, bres);
  k_rigid<<<dim3(L), dim3(256), 0, stream>>>(proj, rot, trans, qg, kt, kgt, vg);
  k_scores<<<dim3(L, H), dim3(256), 0, stream>>>(proj, qg, kt, kgt, bres, ridx, mask, hws, attn);
  k_av<<<dim3(L, H), dim3(256), 0, stream>>>(attn, proj, vg, rot, trans, cat);
  k_opair<<<dim3(L), dim3(256), 0, stream>>>(attn, z, murs, lnzs, lnzb, ridx, cat);
  k_final<<<dim3(L/4), dim3(256), 0, stream>>>(cat, wout, bout, out);
}

// Round 3
// 675.404 us; speedup vs baseline: 1.2421x; 1.2421x over previous
//
#include <hip/hip_runtime.h>
#include <hip/hip_bf16.h>

#define L 1152
#define NRES 384
#define CS 256
#define CZ 128
#define H 8
#define CH 16
#define PQ 8
#define PV 12
#define PROJC 1056

// workspace offsets (in floats)
#define OFF_SLN  0L          // 1152*256      = 294912
#define OFF_PROJ 294912L     // 1152*1056     = 1216512
#define OFF_QG   1511424L    // 1152*192      = 221184
#define OFF_KT   1732608L    // 8*16*1152     = 147456
#define OFF_KGT  1880064L    // 8*24*1152     = 221184
#define OFF_VG   2101248L    // 1152*288      = 331776
#define OFF_BRES 2433024L    // 8*147456     = 1179648 (transposed [h][rp])
#define OFF_MURS 3612672L    // 384*384*2     = 294912
#define OFF_ATTN 3907584L    // 8*1152*1152   = 10616832
#define OFF_CAT  14524416L   // 1152*1536     = 1769472
// total fp32: 16293888 floats = 65.2 MB

// ---------------- kernel 1: LayerNorm(s) -> fp32 -------------------
__global__ __launch_bounds__(256) void k_ln_s(const float* s, const float* sc, const float* bi, float* sln){
  int l = blockIdx.x, t = threadIdx.x;
  __shared__ float red[CS];
  float x = s[(long)l*CS + t];
  red[t] = x; __syncthreads();
  for(int st=128; st>0; st>>=1){ if(t<st) red[t]+=red[t+st]; __syncthreads(); }
  float mu = red[0] * (1.f/CS); __syncthreads();
  float d = x - mu;
  red[t] = d*d; __syncthreads();
  for(int st=128; st>0; st>>=1){ if(t<st) red[t]+=red[t+st]; __syncthreads(); }
  float var = red[0]*(1.f/CS);
  sln[(long)l*CS + t] = d*rsqrtf(var + 1e-5f)*sc[t] + bi[t];
}

// ---------------- kernel 2: all six projections --------------------
__global__ __launch_bounds__(256) void k_proj(const float* sln, float* proj,
                       const float* wq, const float* wk, const float* wv,
                       const float* wqp, const float* wkp, const float* wvp){
  int l0 = blockIdx.x*4, t = threadIdx.x;
  __shared__ float sle[4][CS];
  for(int i=t;i<4*CS;i+=256) sle[i>>8][i&255] = sln[(long)(l0 + (i>>8))*CS + (i&255)];
  __syncthreads();
#define DO_PROJ(W, C, OFFC) \
  for(int c=t;c<(C);c+=256){ float a0=0,a1=0,a2=0,a3=0; \
    for(int k=0;k<CS;k++){ float w=W[(long)k*(C)+c]; \
      a0+=sle[0][k]*w; a1+=sle[1][k]*w; a2+=sle[2][k]*w; a3+=sle[3][k]*w;} \
    proj[(long)(l0+0)*PROJC+(OFFC)+c]=a0; proj[(long)(l0+1)*PROJC+(OFFC)+c]=a1; \
    proj[(long)(l0+2)*PROJC+(OFFC)+c]=a2; proj[(long)(l0+3)*PROJC+(OFFC)+c]=a3; }
  DO_PROJ(wq, 128, 0)
  DO_PROJ(wk, 128, 128)
  DO_PROJ(wv, 128, 256)
  DO_PROJ(wqp,192, 384)
  DO_PROJ(wkp,192, 576)
  DO_PROJ(wvp,288, 768)
#undef DO_PROJ
}

// ---------------- kernel 3: LayerNorm(z) stats + b_res = z_ln @ w_b
// 32 rows/block; each thread owns 16 contiguous cols of one row in regs.
// bres[h] = rstd*(sum_c x_c*swb[c][h] - mu*S[h]) + B[h],
//   swb[c][h]=sc[c]*wb[c][h], S[h]=sum swb, B[h]=sum bi[c]*wb[c][h].
__global__ __launch_bounds__(256) void k_ln_z(const float* z, const float* sc, const float* bi,
                       const float* wb, float* murs, float* bres_t){
  int t = threadIdx.x;
  long rp0 = (long)blockIdx.x*32;
  int r = t>>3, part = t&7;
  long rp = rp0 + r;
  __shared__ __align__(16) float swb[8*132];   // [h][c] padded to 132
  __shared__ float SB[8][2];
  const float4* z4 = (const float4*)z;
  float4 x0 = z4[rp*32 + part*4 + 0];
  float4 x1 = z4[rp*32 + part*4 + 1];
  float4 x2 = z4[rp*32 + part*4 + 2];
  float4 x3 = z4[rp*32 + part*4 + 3];
  #pragma unroll
  for(int k2=0;k2<4;k2++){
    int e = t + k2*256; int h = e>>7, c = e&127;
    swb[h*132 + c] = sc[c]*wb[(long)c*8 + h];
  }
  __syncthreads();
  if(t < 64){
    int h = t>>3, seg = t&7;
    float S=0, Bv=0;
    #pragma unroll
    for(int i=0;i<16;i++){
      int c = seg*16+i;
      S  += swb[h*132+c];
      Bv += bi[c]*wb[(long)c*8 + h];
    }
    #pragma unroll
    for(int off=1;off<8;off<<=1){ S += __shfl_xor(S,off,64); Bv += __shfl_xor(Bv,off,64); }
    if(seg==0){ SB[h][0]=S; SB[h][1]=Bv; }
  }
  // row stats (E[x^2]-mu^2)
  float s1 = x0.x+x0.y+x0.z+x0.w + x1.x+x1.y+x1.z+x1.w
           + x2.x+x2.y+x2.z+x2.w + x3.x+x3.y+x3.z+x3.w;
  float s2 = x0.x*x0.x+x0.y*x0.y+x0.z*x0.z+x0.w*x0.w
           + x1.x*x1.x+x1.y*x1.y+x1.z*x1.z+x1.w*x1.w
           + x2.x*x2.x+x2.y*x2.y+x2.z*x2.z+x2.w*x2.w
           + x3.x*x3.x+x3.y*x3.y+x3.z*x3.z+x3.w*x3.w;
  #pragma unroll
  for(int off=1;off<8;off<<=1){ s1 += __shfl_xor(s1,off,64); s2 += __shfl_xor(s2,off,64); }
  float mu = s1*(1.f/CZ);
  float var = s2*(1.f/CZ) - mu*mu;
  float rstd = rsqrtf(var + 1e-5f);
  if(part==0){ murs[rp*2]=mu; murs[rp*2+1]=rstd; }
  // dot(x, swb[h]) for all 8 h
  float acc[8];
  const float4* swb4 = (const float4*)swb;  // 33 float4 per h-row
  #pragma unroll
  for(int h=0;h<8;h++){
    float4 wa = swb4[h*33 + part*4 + 0];
    float4 wbv= swb4[h*33 + part*4 + 1];
    float4 wc = swb4[h*33 + part*4 + 2];
    float4 wd = swb4[h*33 + part*4 + 3];
    acc[h] = x0.x*wa.x + x0.y*wa.y + x0.z*wa.z + x0.w*wa.w
           + x1.x*wbv.x+ x1.y*wbv.y+ x1.z*wbv.z+ x1.w*wbv.w
           + x2.x*wc.x + x2.y*wc.y + x2.z*wc.z + x2.w*wc.w
           + x3.x*wd.x + x3.y*wd.y + x3.z*wd.z + x3.w*wd.w;
  }
  #pragma unroll
  for(int off=1;off<8;off<<=1){
    #pragma unroll
    for(int h=0;h<8;h++) acc[h] += __shfl_xor(acc[h],off,64);
  }
  __syncthreads();
  if(part==0){
    #pragma unroll
    for(int h=0;h<8;h++)
      bres_t[(long)h*147456 + rp] = rstd*(acc[h] - mu*SB[h][0]) + SB[h][1];
  }
}

// ---------------- kernel 4: rigid transforms -----------------------
// q_g[l][h*24+m], k_t[h*16+c][l], kg_t[h*24+m][l], v_g[l][h*36+m]
__global__ __launch_bounds__(256) void k_rigid(const float* proj, const float* rot, const float* trans,
                        float* qg, float* kt, float* kgt, float* vg){
  int l = blockIdx.x, t = threadIdx.x;
  __shared__ float R[9], T[3];
  if(t<9) R[t]=rot[(long)l*9+t];
  if(t<3) T[t]=trans[(long)l*3+t];
  __syncthreads();
  const float* pr = proj + (long)l*PROJC;
  if(t < 192){
    int h=t/24, m=t%24, p=m/3, i=m%3;
    {
      float a = R[i*3+0]*pr[384+h*24+p*3+0] + R[i*3+1]*pr[384+h*24+p*3+1]
              + R[i*3+2]*pr[384+h*24+p*3+2] + T[i];
      qg[(long)l*192+t]=a;
    }
    {
      float a = R[i*3+0]*pr[576+h*24+p*3+0] + R[i*3+1]*pr[576+h*24+p*3+1]
              + R[i*3+2]*pr[576+h*24+p*3+2] + T[i];
      kgt[(long)t*L + l]=a;
    }
  }
  if(t<128) kt[(long)t*L + l] = pr[128+t];
  for(int it=t; it<288; it+=256){
    int h=it/36, m=it%36, p=m/3, i=m%3;
    float a = R[i*3+0]*pr[768+h*36+p*3+0] + R[i*3+1]*pr[768+h*36+p*3+1]
            + R[i*3+2]*pr[768+h*36+p*3+2] + T[i];
    vg[(long)l*288+it]=a;
  }
}

// ---------------- kernel 5: attention scores + softmax -------------
__global__ __launch_bounds__(256) void k_scores(const float* proj, const float* qg, const float* kt,
                         const float* kgt, const float* bres_t, const int* ridx,
                         const float* mask, const float* hws, float* attn){
  int l = blockIdx.x, h = blockIdx.y, t = threadIdx.x;
  __shared__ float qls[CH], qgs[24], red[256];
  if(t<CH) qls[t]=proj[(long)l*PROJC + h*CH + t];
  if(t<24) qgs[t]=qg[(long)l*192 + h*24 + t];
  __syncthreads();
  float qq=0;
  #pragma unroll
  for(int m=0;m<24;m++) qq+=qgs[m]*qgs[m];
  float hw = log1pf(expf(hws[h]))*0.09622504486493764f;  // softplus * sqrt(1/108)
  int rl = ridx[l];
  const float* bb = bres_t + (long)h*147456 + (long)rl*NRES;
  float areg[5]; int cnt=0;
  float lmax=-1e30f;
  for(int j=t; j<L; j+=256){
    float dq=0;
    #pragma unroll
    for(int c=0;c<CH;c++) dq += qls[c]*kt[(long)(h*CH+c)*L + j];
    float kk=0, qkp=0;
    #pragma unroll
    for(int m=0;m<24;m++){ float kv = kgt[(long)(h*24+m)*L + j]; qkp+=qgs[m]*kv; kk+=kv*kv; }
    float bias = bb[ridx[j]];
    float a = dq*0.14433756729740643f + 0.5773502691896258f*bias
            - 0.5f*hw*(qq + kk - 2.f*qkp)
            + (mask[j]-1.f)*1e9f;
    areg[cnt++]=a;
    lmax = fmaxf(lmax, a);
  }
  red[t]=lmax; __syncthreads();
  for(int st=128;st>0;st>>=1){ if(t<st) red[t]=fmaxf(red[t],red[t+st]); __syncthreads(); }
  float amax = red[0]; __syncthreads();
  float lsum=0;
  for(int i=0;i<cnt;i++){ areg[i]=expf(areg[i]-amax); lsum+=areg[i]; }
  red[t]=lsum; __syncthreads();
  for(int st=128;st>0;st>>=1){ if(t<st) red[t]+=red[t+st]; __syncthreads(); }
  float inv = 1.f/red[0];
  float* arow = attn + ((long)h*L + l)*L;
  cnt=0;
  for(int j=t;j<L;j+=256) arow[j] = areg[cnt++]*inv;
}

// ---------------- kernel 6: o = attn@v, o_pt = rot^T(attn@v_g - t), norms
__global__ __launch_bounds__(256) void k_av(const float* attn, const float* proj, const float* vg,
                     const float* rot, const float* trans, float* cat){
  int l=blockIdx.x, h=blockIdx.y, t=threadIdx.x;
  __shared__ float as[L];
  __shared__ float red[256];
  __shared__ float fin[64];
  const float* arow = attn + ((long)h*L+l)*L;
  for(int j=t;j<L;j+=256) as[j]=arow[j];
  __syncthreads();
  int d=t&63, ch=t>>6;
  float acc=0;
  int j0=ch*288, j1=j0+288;
  if(d<16){
    for(int j=j0;j<j1;j++) acc += as[j]*proj[(long)j*PROJC + 256 + h*CH + d];
  } else if(d<52){
    int m=d-16;
    for(int j=j0;j<j1;j++) acc += as[j]*vg[(long)j*288 + h*36 + m];
  }
  red[t]=acc; __syncthreads();
  if(t<64) fin[t]=red[t]+red[t+64]+red[t+128]+red[t+192];
  __syncthreads();
  float* crow = cat + (long)l*1536 + h*192;
  if(t<16) crow[t]=fin[t];
  if(t>=16 && t<28){
    int p=t-16;
    float og[3];
    #pragma unroll
    for(int j=0;j<3;j++) og[j]=fin[16+p*3+j]-trans[(long)l*3+j];
    float nrm=0;
    #pragma unroll
    for(int i=0;i<3;i++){
      float v = rot[(long)l*9+0*3+i]*og[0]
              + rot[(long)l*9+1*3+i]*og[1]
              + rot[(long)l*9+2*3+i]*og[2];
      crow[16+p*3+i]=v; nrm+=v*v;
    }
    crow[52+p]=sqrtf(nrm+1e-8f);
  }
}

// ---------------- kernel 7: o_pair (z_ln recomputed on the fly) ----
__global__ __launch_bounds__(256) void k_opair(const float* attn, const float* z, const float* murs,
                        const float* sc, const float* bi, const int* ridx, float* cat){
  int l=blockIdx.x, t=threadIdx.x;
  __shared__ float ar[H][NRES];
  for(int it=t; it<H*NRES; it+=256){
    int h=it/NRES, n=it%NRES;
    const float* arow = attn + ((long)h*L+l)*L + n*3;
    ar[h][n]=arow[0]+arow[1]+arow[2];
  }
  __syncthreads();
  int c=t&127, hg=(t>>7)*4;
  int rl=ridx[l];
  float scc=sc[c], bic=bi[c];
  float acc0=0,acc1=0,acc2=0,acc3=0;
  const float* zrow = z + ((long)rl*NRES)*CZ + c;
  const float* mr = murs + (long)rl*NRES*2;
  for(int n=0;n<NRES;n++){
    float zv=(zrow[(long)n*CZ] - mr[n*2])*mr[n*2+1]*scc + bic;
    acc0+=ar[hg+0][n]*zv; acc1+=ar[hg+1][n]*zv;
    acc2+=ar[hg+2][n]*zv; acc3+=ar[hg+3][n]*zv;
  }
  float* crow = cat + (long)l*1536;
  crow[(hg+0)*192+64+c]=acc0; crow[(hg+1)*192+64+c]=acc1;
  crow[(hg+2)*192+64+c]=acc2; crow[(hg+3)*192+64+c]=acc3;
}

// ---------------- kernel 8: final GEMM + bias ----------------------
__global__ __launch_bounds__(256) void k_final(const float* cat, const float* wout, const float* bout, float* out){
  int l0=blockIdx.x*4, t=threadIdx.x;
  __shared__ float cs4[4][1536];
  for(int i=t;i<4*1536;i+=256) cs4[i/1536][i%1536]=cat[(long)(l0+i/1536)*1536 + (i%1536)];
  __syncthreads();
  float b0=bout[t];
  float a0=b0,a1=b0,a2=b0,a3=b0;
  for(int k=0;k<1536;k++){
    float w=wout[(long)k*CS+t];
    a0+=cs4[0][k]*w; a1+=cs4[1][k]*w; a2+=cs4[2][k]*w; a3+=cs4[3][k]*w;
  }
  out[(long)(l0+0)*CS+t]=a0;
  out[(long)(l0+1)*CS+t]=a1;
  out[(long)(l0+2)*CS+t]=a2;
  out[(long)(l0+3)*CS+t]=a3;
}

extern "C" void kernel_launch(void* const* d_in, const int* in_sizes, int n_in,
                              void* d_out, int out_size, void* d_ws, size_t ws_size,
                              hipStream_t stream) {
  const float* s      = (const float*)d_in[0];
  const float* z      = (const float*)d_in[1];
  const float* rot    = (const float*)d_in[2];
  const float* trans  = (const float*)d_in[3];
  const float* mask   = (const float*)d_in[4];
  const float* lnss   = (const float*)d_in[5];
  const float* lnsb   = (const float*)d_in[6];
  const float* lnzs   = (const float*)d_in[7];
  const float* lnzb   = (const float*)d_in[8];
  const float* wq     = (const float*)d_in[9];
  const float* wk     = (const float*)d_in[10];
  const float* wv     = (const float*)d_in[11];
  const float* wqp    = (const float*)d_in[12];
  const float* wkp    = (const float*)d_in[13];
  const float* wvp    = (const float*)d_in[14];
  const float* wb     = (const float*)d_in[15];
  const float* hws    = (const float*)d_in[16];
  const float* wout   = (const float*)d_in[17];
  const float* bout   = (const float*)d_in[18];
  const int*  ridx    = (const int*)d_in[19];

  float* ws  = (float*)d_ws;
  float* out = (float*)d_out;

  float* sln  = ws + OFF_SLN;
  float* proj = ws + OFF_PROJ;
  float* qg   = ws + OFF_QG;
  float* kt   = ws + OFF_KT;
  float* kgt  = ws + OFF_KGT;
  float* vg   = ws + OFF_VG;
  float* bres = ws + OFF_BRES;
  float* murs = ws + OFF_MURS;
  float* attn = ws + OFF_ATTN;
  float* cat  = ws + OFF_CAT;

  k_ln_s<<<dim3(L), dim3(CS), 0, stream>>>(s, lnss, lnsb, sln);
  k_proj<<<dim3(L/4), dim3(256), 0, stream>>>(sln, proj, wq, wk, wv, wqp, wkp, wvp);
  k_ln_z<<<dim3(NRES*NRES/32), dim3(256), 0, stream>>>(z, lnzs, lnzb, wb, murs, bres);
  k_rigid<<<dim3(L), dim3(256), 0, stream>>>(proj, rot, trans, qg, kt, kgt, vg);
  k_scores<<<dim3(L, H), dim3(256), 0, stream>>>(proj, qg, kt, kgt, bres, ridx, mask, hws, attn);
  k_av<<<dim3(L, H), dim3(256), 0, stream>>>(attn, proj, vg, rot, trans, cat);
  k_opair<<<dim3(L), dim3(256), 0, stream>>>(attn, z, murs, lnzs, lnzb, ridx, cat);
  k_final<<<dim3(L/4), dim3(256), 0, stream>>>(cat, wout, bout, out);
}

// Round 4
// 554.644 us; speedup vs baseline: 1.5125x; 1.2177x over previous
//
#include <hip/hip_runtime.h>
#include <hip/hip_bf16.h>

#define L 1152
#define NRES 384
#define CS 256
#define CZ 128
#define H 8
#define CH 16
#define PQ 8
#define PV 12
#define PROJC 1056

// workspace offsets (in floats)
#define OFF_SLN  0L          // 1152*256      = 294912
#define OFF_PROJ 294912L     // 1152*1056     = 1216512
#define OFF_QG   1511424L    // 1152*192      = 221184
#define OFF_KT   1732608L    // 8*16*1152     = 147456
#define OFF_KGT  1880064L    // 8*24*1152     = 221184
#define OFF_VCAT 2101248L    // 8*1152*64     = 589824
#define OFF_BRES 2691072L    // 8*147456      = 1179648 (transposed [h][rp])
#define OFF_MURS 3870720L    // 384*384*2     = 294912
#define OFF_ATTN 4165632L    // 8*1152*1152   = 10616832
#define OFF_CAT  14782464L   // 1152*1536     = 1769472
// total fp32: 16551936 floats = 66.2 MB

// ---------------- kernel 1: LayerNorm(s) -> fp32 -------------------
__global__ __launch_bounds__(256) void k_ln_s(const float* s, const float* sc, const float* bi, float* sln){
  int l = blockIdx.x, t = threadIdx.x;
  __shared__ float red[CS];
  float x = s[(long)l*CS + t];
  red[t] = x; __syncthreads();
  for(int st=128; st>0; st>>=1){ if(t<st) red[t]+=red[t+st]; __syncthreads(); }
  float mu = red[0] * (1.f/CS); __syncthreads();
  float d = x - mu;
  red[t] = d*d; __syncthreads();
  for(int st=128; st>0; st>>=1){ if(t<st) red[t]+=red[t+st]; __syncthreads(); }
  float var = red[0]*(1.f/CS);
  sln[(long)l*CS + t] = d*rsqrtf(var + 1e-5f)*sc[t] + bi[t];
}

// ---------------- kernel 2: all six projections --------------------
__global__ __launch_bounds__(256) void k_proj(const float* sln, float* proj,
                       const float* wq, const float* wk, const float* wv,
                       const float* wqp, const float* wkp, const float* wvp){
  int l0 = blockIdx.x*4, t = threadIdx.x;
  __shared__ float sle[4][CS];
  for(int i=t;i<4*CS;i+=256) sle[i>>8][i&255] = sln[(long)(l0 + (i>>8))*CS + (i&255)];
  __syncthreads();
#define DO_PROJ(W, C, OFFC) \
  for(int c=t;c<(C);c+=256){ float a0=0,a1=0,a2=0,a3=0; \
    for(int k=0;k<CS;k++){ float w=W[(long)k*(C)+c]; \
      a0+=sle[0][k]*w; a1+=sle[1][k]*w; a2+=sle[2][k]*w; a3+=sle[3][k]*w;} \
    proj[(long)(l0+0)*PROJC+(OFFC)+c]=a0; proj[(long)(l0+1)*PROJC+(OFFC)+c]=a1; \
    proj[(long)(l0+2)*PROJC+(OFFC)+c]=a2; proj[(long)(l0+3)*PROJC+(OFFC)+c]=a3; }
  DO_PROJ(wq, 128, 0)
  DO_PROJ(wk, 128, 128)
  DO_PROJ(wv, 128, 256)
  DO_PROJ(wqp,192, 384)
  DO_PROJ(wkp,192, 576)
  DO_PROJ(wvp,288, 768)
#undef DO_PROJ
}

// ---------------- kernel 3: LayerNorm(z) stats + b_res = z_ln @ w_b
__global__ __launch_bounds__(256) void k_ln_z(const float* z, const float* sc, const float* bi,
                       const float* wb, float* murs, float* bres_t){
  int t = threadIdx.x;
  long rp0 = (long)blockIdx.x*32;
  int r = t>>3, part = t&7;
  long rp = rp0 + r;
  __shared__ __align__(16) float swb[8*132];   // [h][c] padded to 132
  __shared__ float SB[8][2];
  const float4* z4 = (const float4*)z;
  float4 x0 = z4[rp*32 + part*4 + 0];
  float4 x1 = z4[rp*32 + part*4 + 1];
  float4 x2 = z4[rp*32 + part*4 + 2];
  float4 x3 = z4[rp*32 + part*4 + 3];
  #pragma unroll
  for(int k2=0;k2<4;k2++){
    int e = t + k2*256; int h = e>>7, c = e&127;
    swb[h*132 + c] = sc[c]*wb[(long)c*8 + h];
  }
  __syncthreads();
  if(t < 64){
    int h = t>>3, seg = t&7;
    float S=0, Bv=0;
    #pragma unroll
    for(int i=0;i<16;i++){
      int c = seg*16+i;
      S  += swb[h*132+c];
      Bv += bi[c]*wb[(long)c*8 + h];
    }
    #pragma unroll
    for(int off=1;off<8;off<<=1){ S += __shfl_xor(S,off,64); Bv += __shfl_xor(Bv,off,64); }
    if(seg==0){ SB[h][0]=S; SB[h][1]=Bv; }
  }
  float s1 = x0.x+x0.y+x0.z+x0.w + x1.x+x1.y+x1.z+x1.w
           + x2.x+x2.y+x2.z+x2.w + x3.x+x3.y+x3.z+x3.w;
  float s2 = x0.x*x0.x+x0.y*x0.y+x0.z*x0.z+x0.w*x0.w
           + x1.x*x1.x+x1.y*x1.y+x1.z*x1.z+x1.w*x1.w
           + x2.x*x2.x+x2.y*x2.y+x2.z*x2.z+x2.w*x2.w
           + x3.x*x3.x+x3.y*x3.y+x3.z*x3.z+x3.w*x3.w;
  #pragma unroll
  for(int off=1;off<8;off<<=1){ s1 += __shfl_xor(s1,off,64); s2 += __shfl_xor(s2,off,64); }
  float mu = s1*(1.f/CZ);
  float var = s2*(1.f/CZ) - mu*mu;
  float rstd = rsqrtf(var + 1e-5f);
  if(part==0){ murs[rp*2]=mu; murs[rp*2+1]=rstd; }
  float acc[8];
  const float4* swb4 = (const float4*)swb;  // 33 float4 per h-row
  #pragma unroll
  for(int h=0;h<8;h++){
    float4 wa = swb4[h*33 + part*4 + 0];
    float4 wbv= swb4[h*33 + part*4 + 1];
    float4 wc = swb4[h*33 + part*4 + 2];
    float4 wd = swb4[h*33 + part*4 + 3];
    acc[h] = x0.x*wa.x + x0.y*wa.y + x0.z*wa.z + x0.w*wa.w
           + x1.x*wbv.x+ x1.y*wbv.y+ x1.z*wbv.z+ x1.w*wbv.w
           + x2.x*wc.x + x2.y*wc.y + x2.z*wc.z + x2.w*wc.w
           + x3.x*wd.x + x3.y*wd.y + x3.z*wd.z + x3.w*wd.w;
  }
  #pragma unroll
  for(int off=1;off<8;off<<=1){
    #pragma unroll
    for(int h=0;h<8;h++) acc[h] += __shfl_xor(acc[h],off,64);
  }
  __syncthreads();
  if(part==0){
    #pragma unroll
    for(int h=0;h<8;h++)
      bres_t[(long)h*147456 + rp] = rstd*(acc[h] - mu*SB[h][0]) + SB[h][1];
  }
}

// ---------------- kernel 4: rigid transforms -----------------------
// q_g[l][h*24+m], k_t[h*16+c][l], kg_t[h*24+m][l], vcat[h][l][64]=v|v_g|0
__global__ __launch_bounds__(256) void k_rigid(const float* proj, const float* rot, const float* trans,
                        float* qg, float* kt, float* kgt, float* vcat){
  int l = blockIdx.x, t = threadIdx.x;
  __shared__ float R[9], T[3];
  if(t<9) R[t]=rot[(long)l*9+t];
  if(t<3) T[t]=trans[(long)l*3+t];
  __syncthreads();
  const float* pr = proj + (long)l*PROJC;
  if(t < 192){
    int h=t/24, m=t%24, p=m/3, i=m%3;
    {
      float a = R[i*3+0]*pr[384+h*24+p*3+0] + R[i*3+1]*pr[384+h*24+p*3+1]
              + R[i*3+2]*pr[384+h*24+p*3+2] + T[i];
      qg[(long)l*192+t]=a;
    }
    {
      float a = R[i*3+0]*pr[576+h*24+p*3+0] + R[i*3+1]*pr[576+h*24+p*3+1]
              + R[i*3+2]*pr[576+h*24+p*3+2] + T[i];
      kgt[(long)t*L + l]=a;
    }
  }
  if(t<128){
    kt[(long)t*L + l] = pr[128+t];
    int h=t>>4, c=t&15;
    vcat[((long)h*L + l)*64 + c] = pr[256+t];
  }
  for(int it=t; it<288; it+=256){
    int h=it/36, m=it%36, p=m/3, i=m%3;
    float a = R[i*3+0]*pr[768+h*36+p*3+0] + R[i*3+1]*pr[768+h*36+p*3+1]
            + R[i*3+2]*pr[768+h*36+p*3+2] + T[i];
    vcat[((long)h*L + l)*64 + 16 + m] = a;
  }
  if(t < 96){
    int h=t/12, d=t%12;
    vcat[((long)h*L + l)*64 + 52 + d] = 0.f;
  }
}

// ---------------- kernel 5: attention scores + softmax -------------
__global__ __launch_bounds__(256) void k_scores(const float* proj, const float* qg, const float* kt,
                         const float* kgt, const float* bres_t, const int* ridx,
                         const float* mask, const float* hws, float* attn){
  int l = blockIdx.x, h = blockIdx.y, t = threadIdx.x;
  __shared__ float qls[CH], qgs[24], red[256];
  if(t<CH) qls[t]=proj[(long)l*PROJC + h*CH + t];
  if(t<24) qgs[t]=qg[(long)l*192 + h*24 + t];
  __syncthreads();
  float qq=0;
  #pragma unroll
  for(int m=0;m<24;m++) qq+=qgs[m]*qgs[m];
  float hw = log1pf(expf(hws[h]))*0.09622504486493764f;  // softplus * sqrt(1/108)
  int rl = ridx[l];
  const float* bb = bres_t + (long)h*147456 + (long)rl*NRES;
  float areg[5]; int cnt=0;
  float lmax=-1e30f;
  for(int j=t; j<L; j+=256){
    float dq=0;
    #pragma unroll
    for(int c=0;c<CH;c++) dq += qls[c]*kt[(long)(h*CH+c)*L + j];
    float kk=0, qkp=0;
    #pragma unroll
    for(int m=0;m<24;m++){ float kv = kgt[(long)(h*24+m)*L + j]; qkp+=qgs[m]*kv; kk+=kv*kv; }
    float bias = bb[ridx[j]];
    float a = dq*0.14433756729740643f + 0.5773502691896258f*bias
            - 0.5f*hw*(qq + kk - 2.f*qkp)
            + (mask[j]-1.f)*1e9f;
    areg[cnt++]=a;
    lmax = fmaxf(lmax, a);
  }
  red[t]=lmax; __syncthreads();
  for(int st=128;st>0;st>>=1){ if(t<st) red[t]=fmaxf(red[t],red[t+st]); __syncthreads(); }
  float amax = red[0]; __syncthreads();
  float lsum=0;
  for(int i=0;i<cnt;i++){ areg[i]=expf(areg[i]-amax); lsum+=areg[i]; }
  red[t]=lsum; __syncthreads();
  for(int st=128;st>0;st>>=1){ if(t<st) red[t]+=red[t+st]; __syncthreads(); }
  float inv = 1.f/red[0];
  float* arow = attn + ((long)h*L + l)*L;
  cnt=0;
  for(int j=t;j<L;j+=256) arow[j] = areg[cnt++]*inv;
}

// ---------------- kernel 6: tiled GEMM o|o_pt + epilogue -----------
__global__ __launch_bounds__(256) void k_av(const float* attn, const float* vcat,
                     const float* rot, const float* trans, float* cat){
  int lb = blockIdx.x, h = blockIdx.y, t = threadIdx.x;
  int l0 = lb*32;
  __shared__ float a_s[64][33];
  __shared__ __align__(16) float v_s[64][68];
  __shared__ __align__(16) float fin_s[32][64];
  int lgrp = t>>4, dgrp = t&15;   // 16 x 16
  float4 acc0 = {0,0,0,0}, acc1 = {0,0,0,0};
  const float* abase = attn + ((long)h*L + l0)*L;
  for(int jc=0; jc<18; jc++){
    int j0 = jc*64;
    {
      int al = t>>3, jj0 = (t&7)*8;
      const float4* src = (const float4*)(abase + (long)al*L + j0 + jj0);
      float4 p0 = src[0], p1 = src[1];
      a_s[jj0+0][al]=p0.x; a_s[jj0+1][al]=p0.y; a_s[jj0+2][al]=p0.z; a_s[jj0+3][al]=p0.w;
      a_s[jj0+4][al]=p1.x; a_s[jj0+5][al]=p1.y; a_s[jj0+6][al]=p1.z; a_s[jj0+7][al]=p1.w;
    }
    {
      int jj = t>>2, seg = t&3;
      const float4* src = (const float4*)(vcat + ((long)h*L + j0 + jj)*64 + seg*16);
      float4 q0=src[0], q1=src[1], q2=src[2], q3=src[3];
      float4* dst = (float4*)&v_s[jj][seg*16];
      dst[0]=q0; dst[1]=q1; dst[2]=q2; dst[3]=q3;
    }
    __syncthreads();
    #pragma unroll 8
    for(int jj=0; jj<64; jj++){
      float a0 = a_s[jj][lgrp*2], a1 = a_s[jj][lgrp*2+1];
      const float4 vv = *(const float4*)&v_s[jj][dgrp*4];
      acc0.x+=a0*vv.x; acc0.y+=a0*vv.y; acc0.z+=a0*vv.z; acc0.w+=a0*vv.w;
      acc1.x+=a1*vv.x; acc1.y+=a1*vv.y; acc1.z+=a1*vv.z; acc1.w+=a1*vv.w;
    }
    __syncthreads();
  }
  *(float4*)&fin_s[lgrp*2+0][dgrp*4] = acc0;
  *(float4*)&fin_s[lgrp*2+1][dgrp*4] = acc1;
  __syncthreads();
  for(int it=t; it<32*16; it+=256){
    int l=it>>4, c=it&15;
    cat[(long)(l0+l)*1536 + h*192 + c] = fin_s[l][c];
  }
  for(int it=t; it<32*12; it+=256){
    int l=it/12, p=it%12;
    long gl = l0+l;
    float og0 = fin_s[l][16+p*3+0]-trans[gl*3+0];
    float og1 = fin_s[l][16+p*3+1]-trans[gl*3+1];
    float og2 = fin_s[l][16+p*3+2]-trans[gl*3+2];
    float* crow = cat + gl*1536 + h*192;
    float nrm=0;
    #pragma unroll
    for(int i=0;i<3;i++){
      float v = rot[gl*9+0+i]*og0 + rot[gl*9+3+i]*og1 + rot[gl*9+6+i]*og2;
      crow[16+p*3+i]=v; nrm+=v*v;
    }
    crow[52+p]=sqrtf(nrm+1e-8f);
  }
}

// ---------------- kernel 7: o_pair (z_ln recomputed on the fly) ----
__global__ __launch_bounds__(256) void k_opair(const float* attn, const float* z, const float* murs,
                        const float* sc, const float* bi, const int* ridx, float* cat){
  int l=blockIdx.x, t=threadIdx.x;
  __shared__ float ar[H][NRES];
  for(int it=t; it<H*NRES; it+=256){
    int h=it/NRES, n=it%NRES;
    const float* arow = attn + ((long)h*L+l)*L + n*3;
    ar[h][n]=arow[0]+arow[1]+arow[2];
  }
  __syncthreads();
  int c=t&127, hg=(t>>7)*4;
  int rl=ridx[l];
  float scc=sc[c], bic=bi[c];
  float acc0=0,acc1=0,acc2=0,acc3=0;
  const float* zrow = z + ((long)rl*NRES)*CZ + c;
  const float* mr = murs + (long)rl*NRES*2;
  for(int n=0;n<NRES;n++){
    float zv=(zrow[(long)n*CZ] - mr[n*2])*mr[n*2+1]*scc + bic;
    acc0+=ar[hg+0][n]*zv; acc1+=ar[hg+1][n]*zv;
    acc2+=ar[hg+2][n]*zv; acc3+=ar[hg+3][n]*zv;
  }
  float* crow = cat + (long)l*1536;
  crow[(hg+0)*192+64+c]=acc0; crow[(hg+1)*192+64+c]=acc1;
  crow[(hg+2)*192+64+c]=acc2; crow[(hg+3)*192+64+c]=acc3;
}

// ---------------- kernel 8: final GEMM + bias ----------------------
__global__ __launch_bounds__(256) void k_final(const float* cat, const float* wout, const float* bout, float* out){
  int l0=blockIdx.x*4, t=threadIdx.x;
  __shared__ float cs4[4][1536];
  for(int i=t;i<4*1536;i+=256) cs4[i/1536][i%1536]=cat[(long)(l0+i/1536)*1536 + (i%1536)];
  __syncthreads();
  float b0=bout[t];
  float a0=b0,a1=b0,a2=b0,a3=b0;
  for(int k=0;k<1536;k++){
    float w=wout[(long)k*CS+t];
    a0+=cs4[0][k]*w; a1+=cs4[1][k]*w; a2+=cs4[2][k]*w; a3+=cs4[3][k]*w;
  }
  out[(long)(l0+0)*CS+t]=a0;
  out[(long)(l0+1)*CS+t]=a1;
  out[(long)(l0+2)*CS+t]=a2;
  out[(long)(l0+3)*CS+t]=a3;
}

extern "C" void kernel_launch(void* const* d_in, const int* in_sizes, int n_in,
                              void* d_out, int out_size, void* d_ws, size_t ws_size,
                              hipStream_t stream) {
  const float* s      = (const float*)d_in[0];
  const float* z      = (const float*)d_in[1];
  const float* rot    = (const float*)d_in[2];
  const float* trans  = (const float*)d_in[3];
  const float* mask   = (const float*)d_in[4];
  const float* lnss   = (const float*)d_in[5];
  const float* lnsb   = (const float*)d_in[6];
  const float* lnzs   = (const float*)d_in[7];
  const float* lnzb   = (const float*)d_in[8];
  const float* wq     = (const float*)d_in[9];
  const float* wk     = (const float*)d_in[10];
  const float* wv     = (const float*)d_in[11];
  const float* wqp    = (const float*)d_in[12];
  const float* wkp    = (const float*)d_in[13];
  const float* wvp    = (const float*)d_in[14];
  const float* wb     = (const float*)d_in[15];
  const float* hws    = (const float*)d_in[16];
  const float* wout   = (const float*)d_in[17];
  const float* bout   = (const float*)d_in[18];
  const int*  ridx    = (const int*)d_in[19];

  float* ws  = (float*)d_ws;
  float* out = (float*)d_out;

  float* sln  = ws + OFF_SLN;
  float* proj = ws + OFF_PROJ;
  float* qg   = ws + OFF_QG;
  float* kt   = ws + OFF_KT;
  float* kgt  = ws + OFF_KGT;
  float* vcat = ws + OFF_VCAT;
  float* bres = ws + OFF_BRES;
  float* murs = ws + OFF_MURS;
  float* attn = ws + OFF_ATTN;
  float* cat  = ws + OFF_CAT;

  k_ln_s<<<dim3(L), dim3(CS), 0, stream>>>(s, lnss, lnsb, sln);
  k_proj<<<dim3(L/4), dim3(256), 0, stream>>>(sln, proj, wq, wk, wv, wqp, wkp, wvp);
  k_ln_z<<<dim3(NRES*NRES/32), dim3(256), 0, stream>>>(z, lnzs, lnzb, wb, murs, bres);
  k_rigid<<<dim3(L), dim3(256), 0, stream>>>(proj, rot, trans, qg, kt, kgt, vcat);
  k_scores<<<dim3(L, H), dim3(256), 0, stream>>>(proj, qg, kt, kgt, bres, ridx, mask, hws, attn);
  k_av<<<dim3(L/32, H), dim3(256), 0, stream>>>(attn, vcat, rot, trans, cat);
  k_opair<<<dim3(L), dim3(256), 0, stream>>>(attn, z, murs, lnzs, lnzb, ridx, cat);
  k_final<<<dim3(L/4), dim3(256), 0, stream>>>(cat, wout, bout, out);
}

// Round 5
// 501.180 us; speedup vs baseline: 1.6739x; 1.1067x over previous
//
#include <hip/hip_runtime.h>
#include <hip/hip_bf16.h>

#define L 1152
#define NRES 384
#define CS 256
#define CZ 128
#define H 8
#define CH 16
#define PQ 8
#define PV 12
#define PROJC 1056

// workspace offsets (in floats)
#define OFF_SLN  0L          // 1152*256      = 294912
#define OFF_PROJ 294912L     // 1152*1056     = 1216512
#define OFF_QCAT 1511424L    // 8*1152*44     = 405504
#define OFF_KCAT 1916928L    // 8*1152*44     = 405504
#define OFF_VCAT 2322432L    // 8*1152*64     = 589824
#define OFF_BRES 2912256L    // 8*147456      = 1179648 (transposed [h][rp])
#define OFF_MURS 4091904L    // 384*384*2     = 294912
#define OFF_ATTN 4386816L    // 8*1152*1152   = 10616832
#define OFF_CAT  15003648L   // 1152*1536     = 1769472
// total fp32: 16773120 floats = 67.1 MB

// ---------------- kernel 1: LayerNorm(s) -> fp32 -------------------
__global__ __launch_bounds__(256) void k_ln_s(const float* s, const float* sc, const float* bi, float* sln){
  int l = blockIdx.x, t = threadIdx.x;
  __shared__ float red[CS];
  float x = s[(long)l*CS + t];
  red[t] = x; __syncthreads();
  for(int st=128; st>0; st>>=1){ if(t<st) red[t]+=red[t+st]; __syncthreads(); }
  float mu = red[0] * (1.f/CS); __syncthreads();
  float d = x - mu;
  red[t] = d*d; __syncthreads();
  for(int st=128; st>0; st>>=1){ if(t<st) red[t]+=red[t+st]; __syncthreads(); }
  float var = red[0]*(1.f/CS);
  sln[(long)l*CS + t] = d*rsqrtf(var + 1e-5f)*sc[t] + bi[t];
}

// ---------------- kernel 2: all six projections --------------------
__global__ __launch_bounds__(256) void k_proj(const float* sln, float* proj,
                       const float* wq, const float* wk, const float* wv,
                       const float* wqp, const float* wkp, const float* wvp){
  int l0 = blockIdx.x*4, t = threadIdx.x;
  __shared__ float sle[4][CS];
  for(int i=t;i<4*CS;i+=256) sle[i>>8][i&255] = sln[(long)(l0 + (i>>8))*CS + (i&255)];
  __syncthreads();
#define DO_PROJ(W, C, OFFC) \
  for(int c=t;c<(C);c+=256){ float a0=0,a1=0,a2=0,a3=0; \
    for(int k=0;k<CS;k++){ float w=W[(long)k*(C)+c]; \
      a0+=sle[0][k]*w; a1+=sle[1][k]*w; a2+=sle[2][k]*w; a3+=sle[3][k]*w;} \
    proj[(long)(l0+0)*PROJC+(OFFC)+c]=a0; proj[(long)(l0+1)*PROJC+(OFFC)+c]=a1; \
    proj[(long)(l0+2)*PROJC+(OFFC)+c]=a2; proj[(long)(l0+3)*PROJC+(OFFC)+c]=a3; }
  DO_PROJ(wq, 128, 0)
  DO_PROJ(wk, 128, 128)
  DO_PROJ(wv, 128, 256)
  DO_PROJ(wqp,192, 384)
  DO_PROJ(wkp,192, 576)
  DO_PROJ(wvp,288, 768)
#undef DO_PROJ
}

// ---------------- kernel 3: LayerNorm(z) stats + b_res = z_ln @ w_b
__global__ __launch_bounds__(256) void k_ln_z(const float* z, const float* sc, const float* bi,
                       const float* wb, float* murs, float* bres_t){
  int t = threadIdx.x;
  long rp0 = (long)blockIdx.x*32;
  int r = t>>3, part = t&7;
  long rp = rp0 + r;
  __shared__ __align__(16) float swb[8*132];   // [h][c] padded to 132
  __shared__ float SB[8][2];
  const float4* z4 = (const float4*)z;
  float4 x0 = z4[rp*32 + part*4 + 0];
  float4 x1 = z4[rp*32 + part*4 + 1];
  float4 x2 = z4[rp*32 + part*4 + 2];
  float4 x3 = z4[rp*32 + part*4 + 3];
  #pragma unroll
  for(int k2=0;k2<4;k2++){
    int e = t + k2*256; int h = e>>7, c = e&127;
    swb[h*132 + c] = sc[c]*wb[(long)c*8 + h];
  }
  __syncthreads();
  if(t < 64){
    int h = t>>3, seg = t&7;
    float S=0, Bv=0;
    #pragma unroll
    for(int i=0;i<16;i++){
      int c = seg*16+i;
      S  += swb[h*132+c];
      Bv += bi[c]*wb[(long)c*8 + h];
    }
    #pragma unroll
    for(int off=1;off<8;off<<=1){ S += __shfl_xor(S,off,64); Bv += __shfl_xor(Bv,off,64); }
    if(seg==0){ SB[h][0]=S; SB[h][1]=Bv; }
  }
  float s1 = x0.x+x0.y+x0.z+x0.w + x1.x+x1.y+x1.z+x1.w
           + x2.x+x2.y+x2.z+x2.w + x3.x+x3.y+x3.z+x3.w;
  float s2 = x0.x*x0.x+x0.y*x0.y+x0.z*x0.z+x0.w*x0.w
           + x1.x*x1.x+x1.y*x1.y+x1.z*x1.z+x1.w*x1.w
           + x2.x*x2.x+x2.y*x2.y+x2.z*x2.z+x2.w*x2.w
           + x3.x*x3.x+x3.y*x3.y+x3.z*x3.z+x3.w*x3.w;
  #pragma unroll
  for(int off=1;off<8;off<<=1){ s1 += __shfl_xor(s1,off,64); s2 += __shfl_xor(s2,off,64); }
  float mu = s1*(1.f/CZ);
  float var = s2*(1.f/CZ) - mu*mu;
  float rstd = rsqrtf(var + 1e-5f);
  if(part==0){ murs[rp*2]=mu; murs[rp*2+1]=rstd; }
  float acc[8];
  const float4* swb4 = (const float4*)swb;  // 33 float4 per h-row
  #pragma unroll
  for(int h=0;h<8;h++){
    float4 wa = swb4[h*33 + part*4 + 0];
    float4 wbv= swb4[h*33 + part*4 + 1];
    float4 wc = swb4[h*33 + part*4 + 2];
    float4 wd = swb4[h*33 + part*4 + 3];
    acc[h] = x0.x*wa.x + x0.y*wa.y + x0.z*wa.z + x0.w*wa.w
           + x1.x*wbv.x+ x1.y*wbv.y+ x1.z*wbv.z+ x1.w*wbv.w
           + x2.x*wc.x + x2.y*wc.y + x2.z*wc.z + x2.w*wc.w
           + x3.x*wd.x + x3.y*wd.y + x3.z*wd.z + x3.w*wd.w;
  }
  #pragma unroll
  for(int off=1;off<8;off<<=1){
    #pragma unroll
    for(int h=0;h<8;h++) acc[h] += __shfl_xor(acc[h],off,64);
  }
  __syncthreads();
  if(part==0){
    #pragma unroll
    for(int h=0;h<8;h++)
      bres_t[(long)h*147456 + rp] = rstd*(acc[h] - mu*SB[h][0]) + SB[h][1];
  }
}

// ---------------- kernel 4: rigid transforms + score-vector packing
// qcat[h][l][44] = [c1*q | hw*qg | rowc | pad], kcat[h][j][44] = [k | kg | colc | pad]
// vcat[h][l][64] = v | v_g | 0
__global__ __launch_bounds__(256) void k_rigid(const float* proj, const float* rot, const float* trans,
                        const float* mask, const float* hws,
                        float* qcat, float* kcat, float* vcat){
  int l = blockIdx.x, t = threadIdx.x;
  __shared__ float R[9], T[3], hwS[8], qgs[192], kgs[192];
  if(t<9) R[t]=rot[(long)l*9+t];
  if(t<3) T[t]=trans[(long)l*3+t];
  if(t>=16 && t<24) hwS[t-16] = log1pf(expf(hws[t-16]))*0.09622504486493764f;
  __syncthreads();
  const float* pr = proj + (long)l*PROJC;
  if(t<128){
    int h=t>>4, c=t&15;
    long base = ((long)h*L + l)*44;
    qcat[base + c] = 0.14433756729740643f * pr[t];
    kcat[base + c] = pr[128+t];
    vcat[((long)h*L + l)*64 + c] = pr[256+t];
  }
  if(t < 192){
    int h=t/24, m=t%24, p=m/3, i=m%3;
    float qa = R[i*3+0]*pr[384+h*24+p*3+0] + R[i*3+1]*pr[384+h*24+p*3+1]
             + R[i*3+2]*pr[384+h*24+p*3+2] + T[i];
    float ka = R[i*3+0]*pr[576+h*24+p*3+0] + R[i*3+1]*pr[576+h*24+p*3+1]
             + R[i*3+2]*pr[576+h*24+p*3+2] + T[i];
    qgs[t]=qa; kgs[t]=ka;
    long base = ((long)h*L + l)*44 + 16 + m;
    qcat[base] = hwS[h]*qa;
    kcat[base] = ka;
  }
  for(int it=t; it<288; it+=256){
    int h=it/36, m=it%36, p=m/3, i=m%3;
    float a = R[i*3+0]*pr[768+h*36+p*3+0] + R[i*3+1]*pr[768+h*36+p*3+1]
            + R[i*3+2]*pr[768+h*36+p*3+2] + T[i];
    vcat[((long)h*L + l)*64 + 16 + m] = a;
  }
  if(t < 96){
    int h=t/12, d=t%12;
    vcat[((long)h*L + l)*64 + 52 + d] = 0.f;
  }
  __syncthreads();
  if(t < 8){
    float qq=0, kk=0;
    #pragma unroll
    for(int m=0;m<24;m++){ qq += qgs[t*24+m]*qgs[t*24+m]; kk += kgs[t*24+m]*kgs[t*24+m]; }
    long base = ((long)t*L + l)*44;
    qcat[base + 40] = -0.5f*hwS[t]*qq;
    kcat[base + 40] = -0.5f*hwS[t]*kk + (mask[l]-1.f)*1e9f;
  }
}

// ---------------- kernel 5: scores GEMM (K=40) + fused softmax -----
// block: 16 l-rows x full j for one h. Thread (lgrp,jgrp) 16x16.
__global__ __launch_bounds__(256) void k_scores(const float* qcat, const float* kcat,
                         const float* bres_t, const int* ridx, float* attn){
  int lb = blockIdx.x, h = blockIdx.y, t = threadIdx.x;
  int lgrp = t>>4, jgrp = t&15;
  int l = lb*16 + lgrp;
  __shared__ __align__(16) float ks[64*44];
  __shared__ int rj_s[64];
  float4 q[10];
  const float4* qrow = (const float4*)(qcat + ((long)h*L + l)*44);
  #pragma unroll
  for(int i=0;i<10;i++) q[i]=qrow[i];
  float rowc = qcat[((long)h*L + l)*44 + 40];
  int rl = ridx[l];
  const float* bb = bres_t + (long)h*147456 + (long)rl*NRES;
  float sc_r[72];
  for(int jc=0;jc<18;jc++){
    int j0=jc*64;
    __syncthreads();
    {
      const float* src = kcat + ((long)h*L + j0)*44;
      #pragma unroll
      for(int i=0;i<11;i++) ks[t + i*256] = src[t + i*256];
      if(t<64) rj_s[t]=ridx[j0+t];
    }
    __syncthreads();
    #pragma unroll
    for(int jj=0;jj<4;jj++){
      int jcol = jgrp + 16*jj;
      const float4* kv = (const float4*)&ks[jcol*44];
      float d=0;
      #pragma unroll
      for(int i=0;i<10;i++){
        float4 a=q[i], b=kv[i];
        d += a.x*b.x + a.y*b.y + a.z*b.z + a.w*b.w;
      }
      float colc = ks[jcol*44+40];
      float bias = bb[rj_s[jcol]];
      sc_r[jc*4+jj] = d + rowc + colc + 0.5773502691896258f*bias;
    }
  }
  float m = sc_r[0];
  #pragma unroll
  for(int i=1;i<72;i++) m = fmaxf(m, sc_r[i]);
  #pragma unroll
  for(int off=1;off<16;off<<=1) m = fmaxf(m, __shfl_xor(m, off, 64));
  float s=0;
  #pragma unroll
  for(int i=0;i<72;i++){ sc_r[i]=__expf(sc_r[i]-m); s+=sc_r[i]; }
  #pragma unroll
  for(int off=1;off<16;off<<=1) s += __shfl_xor(s, off, 64);
  float inv=1.f/s;
  float* arow = attn + ((long)h*L + l)*L;
  #pragma unroll
  for(int jc=0;jc<18;jc++){
    #pragma unroll
    for(int jj=0;jj<4;jj++)
      arow[jc*64 + jgrp + 16*jj] = sc_r[jc*4+jj]*inv;
  }
}

// ---------------- kernel 6: tiled GEMM o|o_pt + epilogue -----------
__global__ __launch_bounds__(256) void k_av(const float* attn, const float* vcat,
                     const float* rot, const float* trans, float* cat){
  int lb = blockIdx.x, h = blockIdx.y, t = threadIdx.x;
  int l0 = lb*32;
  __shared__ float a_s[64][33];
  __shared__ __align__(16) float v_s[64][68];
  __shared__ __align__(16) float fin_s[32][64];
  int lgrp = t>>4, dgrp = t&15;   // 16 x 16
  float4 acc0 = {0,0,0,0}, acc1 = {0,0,0,0};
  const float* abase = attn + ((long)h*L + l0)*L;
  for(int jc=0; jc<18; jc++){
    int j0 = jc*64;
    {
      int al = t>>3, jj0 = (t&7)*8;
      const float4* src = (const float4*)(abase + (long)al*L + j0 + jj0);
      float4 p0 = src[0], p1 = src[1];
      a_s[jj0+0][al]=p0.x; a_s[jj0+1][al]=p0.y; a_s[jj0+2][al]=p0.z; a_s[jj0+3][al]=p0.w;
      a_s[jj0+4][al]=p1.x; a_s[jj0+5][al]=p1.y; a_s[jj0+6][al]=p1.z; a_s[jj0+7][al]=p1.w;
    }
    {
      int jj = t>>2, seg = t&3;
      const float4* src = (const float4*)(vcat + ((long)h*L + j0 + jj)*64 + seg*16);
      float4 q0=src[0], q1=src[1], q2=src[2], q3=src[3];
      float4* dst = (float4*)&v_s[jj][seg*16];
      dst[0]=q0; dst[1]=q1; dst[2]=q2; dst[3]=q3;
    }
    __syncthreads();
    #pragma unroll 8
    for(int jj=0; jj<64; jj++){
      float a0 = a_s[jj][lgrp*2], a1 = a_s[jj][lgrp*2+1];
      const float4 vv = *(const float4*)&v_s[jj][dgrp*4];
      acc0.x+=a0*vv.x; acc0.y+=a0*vv.y; acc0.z+=a0*vv.z; acc0.w+=a0*vv.w;
      acc1.x+=a1*vv.x; acc1.y+=a1*vv.y; acc1.z+=a1*vv.z; acc1.w+=a1*vv.w;
    }
    __syncthreads();
  }
  *(float4*)&fin_s[lgrp*2+0][dgrp*4] = acc0;
  *(float4*)&fin_s[lgrp*2+1][dgrp*4] = acc1;
  __syncthreads();
  for(int it=t; it<32*16; it+=256){
    int l=it>>4, c=it&15;
    cat[(long)(l0+l)*1536 + h*192 + c] = fin_s[l][c];
  }
  for(int it=t; it<32*12; it+=256){
    int l=it/12, p=it%12;
    long gl = l0+l;
    float og0 = fin_s[l][16+p*3+0]-trans[gl*3+0];
    float og1 = fin_s[l][16+p*3+1]-trans[gl*3+1];
    float og2 = fin_s[l][16+p*3+2]-trans[gl*3+2];
    float* crow = cat + gl*1536 + h*192;
    float nrm=0;
    #pragma unroll
    for(int i=0;i<3;i++){
      float v = rot[gl*9+0+i]*og0 + rot[gl*9+3+i]*og1 + rot[gl*9+6+i]*og2;
      crow[16+p*3+i]=v; nrm+=v*v;
    }
    crow[52+p]=sqrtf(nrm+1e-8f);
  }
}

// ---------------- kernel 7: o_pair (z_ln recomputed on the fly) ----
__global__ __launch_bounds__(256) void k_opair(const float* attn, const float* z, const float* murs,
                        const float* sc, const float* bi, const int* ridx, float* cat){
  int l=blockIdx.x, t=threadIdx.x;
  __shared__ float ar[H][NRES];
  for(int it=t; it<H*NRES; it+=256){
    int h=it/NRES, n=it%NRES;
    const float* arow = attn + ((long)h*L+l)*L + n*3;
    ar[h][n]=arow[0]+arow[1]+arow[2];
  }
  __syncthreads();
  int c=t&127, hg=(t>>7)*4;
  int rl=ridx[l];
  float scc=sc[c], bic=bi[c];
  float acc0=0,acc1=0,acc2=0,acc3=0;
  const float* zrow = z + ((long)rl*NRES)*CZ + c;
  const float* mr = murs + (long)rl*NRES*2;
  for(int n=0;n<NRES;n++){
    float zv=(zrow[(long)n*CZ] - mr[n*2])*mr[n*2+1]*scc + bic;
    acc0+=ar[hg+0][n]*zv; acc1+=ar[hg+1][n]*zv;
    acc2+=ar[hg+2][n]*zv; acc3+=ar[hg+3][n]*zv;
  }
  float* crow = cat + (long)l*1536;
  crow[(hg+0)*192+64+c]=acc0; crow[(hg+1)*192+64+c]=acc1;
  crow[(hg+2)*192+64+c]=acc2; crow[(hg+3)*192+64+c]=acc3;
}

// ---------------- kernel 8: final GEMM + bias ----------------------
__global__ __launch_bounds__(256) void k_final(const float* cat, const float* wout, const float* bout, float* out){
  int l0=blockIdx.x*4, t=threadIdx.x;
  __shared__ float cs4[4][1536];
  for(int i=t;i<4*1536;i+=256) cs4[i/1536][i%1536]=cat[(long)(l0+i/1536)*1536 + (i%1536)];
  __syncthreads();
  float b0=bout[t];
  float a0=b0,a1=b0,a2=b0,a3=b0;
  for(int k=0;k<1536;k++){
    float w=wout[(long)k*CS+t];
    a0+=cs4[0][k]*w; a1+=cs4[1][k]*w; a2+=cs4[2][k]*w; a3+=cs4[3][k]*w;
  }
  out[(long)(l0+0)*CS+t]=a0;
  out[(long)(l0+1)*CS+t]=a1;
  out[(long)(l0+2)*CS+t]=a2;
  out[(long)(l0+3)*CS+t]=a3;
}

extern "C" void kernel_launch(void* const* d_in, const int* in_sizes, int n_in,
                              void* d_out, int out_size, void* d_ws, size_t ws_size,
                              hipStream_t stream) {
  const float* s      = (const float*)d_in[0];
  const float* z      = (const float*)d_in[1];
  const float* rot    = (const float*)d_in[2];
  const float* trans  = (const float*)d_in[3];
  const float* mask   = (const float*)d_in[4];
  const float* lnss   = (const float*)d_in[5];
  const float* lnsb   = (const float*)d_in[6];
  const float* lnzs   = (const float*)d_in[7];
  const float* lnzb   = (const float*)d_in[8];
  const float* wq     = (const float*)d_in[9];
  const float* wk     = (const float*)d_in[10];
  const float* wv     = (const float*)d_in[11];
  const float* wqp    = (const float*)d_in[12];
  const float* wkp    = (const float*)d_in[13];
  const float* wvp    = (const float*)d_in[14];
  const float* wb     = (const float*)d_in[15];
  const float* hws    = (const float*)d_in[16];
  const float* wout   = (const float*)d_in[17];
  const float* bout   = (const float*)d_in[18];
  const int*  ridx    = (const int*)d_in[19];

  float* ws  = (float*)d_ws;
  float* out = (float*)d_out;

  float* sln  = ws + OFF_SLN;
  float* proj = ws + OFF_PROJ;
  float* qcat = ws + OFF_QCAT;
  float* kcat = ws + OFF_KCAT;
  float* vcat = ws + OFF_VCAT;
  float* bres = ws + OFF_BRES;
  float* murs = ws + OFF_MURS;
  float* attn = ws + OFF_ATTN;
  float* cat  = ws + OFF_CAT;

  k_ln_s<<<dim3(L), dim3(CS), 0, stream>>>(s, lnss, lnsb, sln);
  k_proj<<<dim3(L/4), dim3(256), 0, stream>>>(sln, proj, wq, wk, wv, wqp, wkp, wvp);
  k_ln_z<<<dim3(NRES*NRES/32), dim3(256), 0, stream>>>(z, lnzs, lnzb, wb, murs, bres);
  k_rigid<<<dim3(L), dim3(256), 0, stream>>>(proj, rot, trans, mask, hws, qcat, kcat, vcat);
  k_scores<<<dim3(L/16, H), dim3(256), 0, stream>>>(qcat, kcat, bres, ridx, attn);
  k_av<<<dim3(L/32, H), dim3(256), 0, stream>>>(attn, vcat, rot, trans, cat);
  k_opair<<<dim3(L), dim3(256), 0, stream>>>(attn, z, murs, lnzs, lnzb, ridx, cat);
  k_final<<<dim3(L/4), dim3(256), 0, stream>>>(cat, wout, bout, out);
}

// Round 6
// 420.649 us; speedup vs baseline: 1.9943x; 1.1914x over previous
//
#include <hip/hip_runtime.h>
#include <hip/hip_bf16.h>

#define L 1152
#define NRES 384
#define CS 256
#define CZ 128
#define H 8
#define CH 16
#define PQ 8
#define PV 12
#define PSTR 1088   // padded projection row stride (17*64)

// workspace offsets (in floats)
#define OFF_SLN  0L          // 1152*256      = 294912
#define OFF_PROJ 294912L     // 1152*1088     = 1253376
#define OFF_WPK  1548288L    // 256*1088      = 278528
#define OFF_QCAT 1826816L    // 8*1152*44     = 405504
#define OFF_KCAT 2232320L    // 8*1152*44     = 405504
#define OFF_VCAT 2637824L    // 8*1152*64     = 589824
#define OFF_BRES 3227648L    // 8*147456      = 1179648 (transposed [h][rp])
#define OFF_MURS 4407296L    // 384*384*2     = 294912
#define OFF_ATTN 4702208L    // 8*1152*1152   = 10616832
#define OFF_CAT  15319040L   // 1152*1536     = 1769472
// total fp32: 17088512 floats = 68.4 MB

// ---------------- kernel 1: LayerNorm(s) -> fp32 -------------------
__global__ __launch_bounds__(256) void k_ln_s(const float* s, const float* sc, const float* bi, float* sln){
  int l = blockIdx.x, t = threadIdx.x;
  __shared__ float red[CS];
  float x = s[(long)l*CS + t];
  red[t] = x; __syncthreads();
  for(int st=128; st>0; st>>=1){ if(t<st) red[t]+=red[t+st]; __syncthreads(); }
  float mu = red[0] * (1.f/CS); __syncthreads();
  float d = x - mu;
  red[t] = d*d; __syncthreads();
  for(int st=128; st>0; st>>=1){ if(t<st) red[t]+=red[t+st]; __syncthreads(); }
  float var = red[0]*(1.f/CS);
  sln[(long)l*CS + t] = d*rsqrtf(var + 1e-5f)*sc[t] + bi[t];
}

// ---------------- kernel 1b: pack six weight mats into wpack[256][1088]
__global__ __launch_bounds__(256) void k_packw(const float* wq, const float* wk, const float* wv,
                        const float* wqp, const float* wkp, const float* wvp, float* wpack){
  int k = blockIdx.x, t = threadIdx.x;
  for(int c=t; c<PSTR; c+=256){
    float v;
    if(c<128)        v = wq [(long)k*128 + c];
    else if(c<256)   v = wk [(long)k*128 + c-128];
    else if(c<384)   v = wv [(long)k*128 + c-256];
    else if(c<576)   v = wqp[(long)k*192 + c-384];
    else if(c<768)   v = wkp[(long)k*192 + c-576];
    else if(c<1056)  v = wvp[(long)k*288 + c-768];
    else             v = 0.f;
    wpack[(long)k*PSTR + c] = v;
  }
}

// ---------------- kernel 2: projections as tiled GEMM --------------
// C[64 l][64 c] per block; K=256 in 8 chunks of 32.
__global__ __launch_bounds__(256) void k_proj(const float* sln, const float* wpack, float* proj){
  int l0 = blockIdx.x*64, c0 = blockIdx.y*64, t = threadIdx.x;
  __shared__ float a_s[32][68];
  __shared__ __align__(16) float w_s[32][68];
  int tr = t>>4, tc = t&15;
  float4 acc[4] = {{0,0,0,0},{0,0,0,0},{0,0,0,0},{0,0,0,0}};
  for(int kc=0; kc<8; kc++){
    int k0 = kc*32;
    {
      int row = t>>2, kk0 = (t&3)*8;
      const float4* src = (const float4*)(sln + (long)(l0+row)*256 + k0 + kk0);
      float4 v0 = src[0], v1 = src[1];
      a_s[kk0+0][row]=v0.x; a_s[kk0+1][row]=v0.y; a_s[kk0+2][row]=v0.z; a_s[kk0+3][row]=v0.w;
      a_s[kk0+4][row]=v1.x; a_s[kk0+5][row]=v1.y; a_s[kk0+6][row]=v1.z; a_s[kk0+7][row]=v1.w;
    }
    #pragma unroll
    for(int kk2=0; kk2<2; kk2++){
      int kk = (t>>4) + 16*kk2;
      *(float4*)&w_s[kk][(t&15)*4] = *(const float4*)(wpack + (long)(k0+kk)*PSTR + c0 + (t&15)*4);
    }
    __syncthreads();
    #pragma unroll 8
    for(int kk=0; kk<32; kk++){
      float4 a4 = *(const float4*)&a_s[kk][tr*4];
      float4 b4 = *(const float4*)&w_s[kk][tc*4];
      acc[0].x+=a4.x*b4.x; acc[0].y+=a4.x*b4.y; acc[0].z+=a4.x*b4.z; acc[0].w+=a4.x*b4.w;
      acc[1].x+=a4.y*b4.x; acc[1].y+=a4.y*b4.y; acc[1].z+=a4.y*b4.z; acc[1].w+=a4.y*b4.w;
      acc[2].x+=a4.z*b4.x; acc[2].y+=a4.z*b4.y; acc[2].z+=a4.z*b4.z; acc[2].w+=a4.z*b4.w;
      acc[3].x+=a4.w*b4.x; acc[3].y+=a4.w*b4.y; acc[3].z+=a4.w*b4.z; acc[3].w+=a4.w*b4.w;
    }
    __syncthreads();
  }
  #pragma unroll
  for(int r=0;r<4;r++)
    *(float4*)(proj + (long)(l0 + tr*4 + r)*PSTR + c0 + tc*4) = acc[r];
}

// ---------------- kernel 3: LayerNorm(z) stats + b_res = z_ln @ w_b
__global__ __launch_bounds__(256) void k_ln_z(const float* z, const float* sc, const float* bi,
                       const float* wb, float* murs, float* bres_t){
  int t = threadIdx.x;
  long rp0 = (long)blockIdx.x*32;
  int r = t>>3, part = t&7;
  long rp = rp0 + r;
  __shared__ __align__(16) float swb[8*132];   // [h][c] padded to 132
  __shared__ float SB[8][2];
  const float4* z4 = (const float4*)z;
  float4 x0 = z4[rp*32 + part*4 + 0];
  float4 x1 = z4[rp*32 + part*4 + 1];
  float4 x2 = z4[rp*32 + part*4 + 2];
  float4 x3 = z4[rp*32 + part*4 + 3];
  #pragma unroll
  for(int k2=0;k2<4;k2++){
    int e = t + k2*256; int h = e>>7, c = e&127;
    swb[h*132 + c] = sc[c]*wb[(long)c*8 + h];
  }
  __syncthreads();
  if(t < 64){
    int h = t>>3, seg = t&7;
    float S=0, Bv=0;
    #pragma unroll
    for(int i=0;i<16;i++){
      int c = seg*16+i;
      S  += swb[h*132+c];
      Bv += bi[c]*wb[(long)c*8 + h];
    }
    #pragma unroll
    for(int off=1;off<8;off<<=1){ S += __shfl_xor(S,off,64); Bv += __shfl_xor(Bv,off,64); }
    if(seg==0){ SB[h][0]=S; SB[h][1]=Bv; }
  }
  float s1 = x0.x+x0.y+x0.z+x0.w + x1.x+x1.y+x1.z+x1.w
           + x2.x+x2.y+x2.z+x2.w + x3.x+x3.y+x3.z+x3.w;
  float s2 = x0.x*x0.x+x0.y*x0.y+x0.z*x0.z+x0.w*x0.w
           + x1.x*x1.x+x1.y*x1.y+x1.z*x1.z+x1.w*x1.w
           + x2.x*x2.x+x2.y*x2.y+x2.z*x2.z+x2.w*x2.w
           + x3.x*x3.x+x3.y*x3.y+x3.z*x3.z+x3.w*x3.w;
  #pragma unroll
  for(int off=1;off<8;off<<=1){ s1 += __shfl_xor(s1,off,64); s2 += __shfl_xor(s2,off,64); }
  float mu = s1*(1.f/CZ);
  float var = s2*(1.f/CZ) - mu*mu;
  float rstd = rsqrtf(var + 1e-5f);
  if(part==0){ murs[rp*2]=mu; murs[rp*2+1]=rstd; }
  float acc[8];
  const float4* swb4 = (const float4*)swb;  // 33 float4 per h-row
  #pragma unroll
  for(int h=0;h<8;h++){
    float4 wa = swb4[h*33 + part*4 + 0];
    float4 wbv= swb4[h*33 + part*4 + 1];
    float4 wc = swb4[h*33 + part*4 + 2];
    float4 wd = swb4[h*33 + part*4 + 3];
    acc[h] = x0.x*wa.x + x0.y*wa.y + x0.z*wa.z + x0.w*wa.w
           + x1.x*wbv.x+ x1.y*wbv.y+ x1.z*wbv.z+ x1.w*wbv.w
           + x2.x*wc.x + x2.y*wc.y + x2.z*wc.z + x2.w*wc.w
           + x3.x*wd.x + x3.y*wd.y + x3.z*wd.z + x3.w*wd.w;
  }
  #pragma unroll
  for(int off=1;off<8;off<<=1){
    #pragma unroll
    for(int h=0;h<8;h++) acc[h] += __shfl_xor(acc[h],off,64);
  }
  __syncthreads();
  if(part==0){
    #pragma unroll
    for(int h=0;h<8;h++)
      bres_t[(long)h*147456 + rp] = rstd*(acc[h] - mu*SB[h][0]) + SB[h][1];
  }
}

// ---------------- kernel 4: rigid transforms + score-vector packing
__global__ __launch_bounds__(256) void k_rigid(const float* proj, const float* rot, const float* trans,
                        const float* mask, const float* hws,
                        float* qcat, float* kcat, float* vcat){
  int l = blockIdx.x, t = threadIdx.x;
  __shared__ float R[9], T[3], hwS[8], qgs[192], kgs[192];
  if(t<9) R[t]=rot[(long)l*9+t];
  if(t<3) T[t]=trans[(long)l*3+t];
  if(t>=16 && t<24) hwS[t-16] = log1pf(expf(hws[t-16]))*0.09622504486493764f;
  __syncthreads();
  const float* pr = proj + (long)l*PSTR;
  if(t<128){
    int h=t>>4, c=t&15;
    long base = ((long)h*L + l)*44;
    qcat[base + c] = 0.14433756729740643f * pr[t];
    kcat[base + c] = pr[128+t];
    vcat[((long)h*L + l)*64 + c] = pr[256+t];
  }
  if(t < 192){
    int h=t/24, m=t%24, p=m/3, i=m%3;
    float qa = R[i*3+0]*pr[384+h*24+p*3+0] + R[i*3+1]*pr[384+h*24+p*3+1]
             + R[i*3+2]*pr[384+h*24+p*3+2] + T[i];
    float ka = R[i*3+0]*pr[576+h*24+p*3+0] + R[i*3+1]*pr[576+h*24+p*3+1]
             + R[i*3+2]*pr[576+h*24+p*3+2] + T[i];
    qgs[t]=qa; kgs[t]=ka;
    long base = ((long)h*L + l)*44 + 16 + m;
    qcat[base] = hwS[h]*qa;
    kcat[base] = ka;
  }
  for(int it=t; it<288; it+=256){
    int h=it/36, m=it%36, p=m/3, i=m%3;
    float a = R[i*3+0]*pr[768+h*36+p*3+0] + R[i*3+1]*pr[768+h*36+p*3+1]
            + R[i*3+2]*pr[768+h*36+p*3+2] + T[i];
    vcat[((long)h*L + l)*64 + 16 + m] = a;
  }
  if(t < 96){
    int h=t/12, d=t%12;
    vcat[((long)h*L + l)*64 + 52 + d] = 0.f;
  }
  __syncthreads();
  if(t < 8){
    float qq=0, kk=0;
    #pragma unroll
    for(int m=0;m<24;m++){ qq += qgs[t*24+m]*qgs[t*24+m]; kk += kgs[t*24+m]*kgs[t*24+m]; }
    long base = ((long)t*L + l)*44;
    qcat[base + 40] = -0.5f*hwS[t]*qq;
    kcat[base + 40] = -0.5f*hwS[t]*kk + (mask[l]-1.f)*1e9f;
  }
}

// ---------------- kernel 5: scores GEMM (K=40) + fused softmax -----
__global__ __launch_bounds__(256) void k_scores(const float* qcat, const float* kcat,
                         const float* bres_t, const int* ridx, float* attn){
  int lb = blockIdx.x, h = blockIdx.y, t = threadIdx.x;
  int lgrp = t>>4, jgrp = t&15;
  int l = lb*16 + lgrp;
  __shared__ __align__(16) float ks[64*44];
  __shared__ int rj_s[64];
  float4 q[10];
  const float4* qrow = (const float4*)(qcat + ((long)h*L + l)*44);
  #pragma unroll
  for(int i=0;i<10;i++) q[i]=qrow[i];
  float rowc = qcat[((long)h*L + l)*44 + 40];
  int rl = ridx[l];
  const float* bb = bres_t + (long)h*147456 + (long)rl*NRES;
  float sc_r[72];
  for(int jc=0;jc<18;jc++){
    int j0=jc*64;
    __syncthreads();
    {
      const float* src = kcat + ((long)h*L + j0)*44;
      #pragma unroll
      for(int i=0;i<11;i++) ks[t + i*256] = src[t + i*256];
      if(t<64) rj_s[t]=ridx[j0+t];
    }
    __syncthreads();
    #pragma unroll
    for(int jj=0;jj<4;jj++){
      int jcol = jgrp + 16*jj;
      const float4* kv = (const float4*)&ks[jcol*44];
      float d=0;
      #pragma unroll
      for(int i=0;i<10;i++){
        float4 a=q[i], b=kv[i];
        d += a.x*b.x + a.y*b.y + a.z*b.z + a.w*b.w;
      }
      float colc = ks[jcol*44+40];
      float bias = bb[rj_s[jcol]];
      sc_r[jc*4+jj] = d + rowc + colc + 0.5773502691896258f*bias;
    }
  }
  float m = sc_r[0];
  #pragma unroll
  for(int i=1;i<72;i++) m = fmaxf(m, sc_r[i]);
  #pragma unroll
  for(int off=1;off<16;off<<=1) m = fmaxf(m, __shfl_xor(m, off, 64));
  float s=0;
  #pragma unroll
  for(int i=0;i<72;i++){ sc_r[i]=__expf(sc_r[i]-m); s+=sc_r[i]; }
  #pragma unroll
  for(int off=1;off<16;off<<=1) s += __shfl_xor(s, off, 64);
  float inv=1.f/s;
  float* arow = attn + ((long)h*L + l)*L;
  #pragma unroll
  for(int jc=0;jc<18;jc++){
    #pragma unroll
    for(int jj=0;jj<4;jj++)
      arow[jc*64 + jgrp + 16*jj] = sc_r[jc*4+jj]*inv;
  }
}

// ---------------- kernel 6: tiled GEMM o|o_pt + epilogue -----------
__global__ __launch_bounds__(256) void k_av(const float* attn, const float* vcat,
                     const float* rot, const float* trans, float* cat){
  int lb = blockIdx.x, h = blockIdx.y, t = threadIdx.x;
  int l0 = lb*32;
  __shared__ float a_s[64][33];
  __shared__ __align__(16) float v_s[64][68];
  __shared__ __align__(16) float fin_s[32][64];
  int lgrp = t>>4, dgrp = t&15;   // 16 x 16
  float4 acc0 = {0,0,0,0}, acc1 = {0,0,0,0};
  const float* abase = attn + ((long)h*L + l0)*L;
  for(int jc=0; jc<18; jc++){
    int j0 = jc*64;
    {
      int al = t>>3, jj0 = (t&7)*8;
      const float4* src = (const float4*)(abase + (long)al*L + j0 + jj0);
      float4 p0 = src[0], p1 = src[1];
      a_s[jj0+0][al]=p0.x; a_s[jj0+1][al]=p0.y; a_s[jj0+2][al]=p0.z; a_s[jj0+3][al]=p0.w;
      a_s[jj0+4][al]=p1.x; a_s[jj0+5][al]=p1.y; a_s[jj0+6][al]=p1.z; a_s[jj0+7][al]=p1.w;
    }
    {
      int jj = t>>2, seg = t&3;
      const float4* src = (const float4*)(vcat + ((long)h*L + j0 + jj)*64 + seg*16);
      float4 q0=src[0], q1=src[1], q2=src[2], q3=src[3];
      float4* dst = (float4*)&v_s[jj][seg*16];
      dst[0]=q0; dst[1]=q1; dst[2]=q2; dst[3]=q3;
    }
    __syncthreads();
    #pragma unroll 8
    for(int jj=0; jj<64; jj++){
      float a0 = a_s[jj][lgrp*2], a1 = a_s[jj][lgrp*2+1];
      const float4 vv = *(const float4*)&v_s[jj][dgrp*4];
      acc0.x+=a0*vv.x; acc0.y+=a0*vv.y; acc0.z+=a0*vv.z; acc0.w+=a0*vv.w;
      acc1.x+=a1*vv.x; acc1.y+=a1*vv.y; acc1.z+=a1*vv.z; acc1.w+=a1*vv.w;
    }
    __syncthreads();
  }
  *(float4*)&fin_s[lgrp*2+0][dgrp*4] = acc0;
  *(float4*)&fin_s[lgrp*2+1][dgrp*4] = acc1;
  __syncthreads();
  for(int it=t; it<32*16; it+=256){
    int l=it>>4, c=it&15;
    cat[(long)(l0+l)*1536 + h*192 + c] = fin_s[l][c];
  }
  for(int it=t; it<32*12; it+=256){
    int l=it/12, p=it%12;
    long gl = l0+l;
    float og0 = fin_s[l][16+p*3+0]-trans[gl*3+0];
    float og1 = fin_s[l][16+p*3+1]-trans[gl*3+1];
    float og2 = fin_s[l][16+p*3+2]-trans[gl*3+2];
    float* crow = cat + gl*1536 + h*192;
    float nrm=0;
    #pragma unroll
    for(int i=0;i<3;i++){
      float v = rot[gl*9+0+i]*og0 + rot[gl*9+3+i]*og1 + rot[gl*9+6+i]*og2;
      crow[16+p*3+i]=v; nrm+=v*v;
    }
    crow[52+p]=sqrtf(nrm+1e-8f);
  }
}

// ---------------- kernel 7: o_pair (z_ln recomputed on the fly) ----
__global__ __launch_bounds__(256) void k_opair(const float* attn, const float* z, const float* murs,
                        const float* sc, const float* bi, const int* ridx, float* cat){
  int l=blockIdx.x, t=threadIdx.x;
  __shared__ float ar[H][NRES];
  for(int it=t; it<H*NRES; it+=256){
    int h=it/NRES, n=it%NRES;
    const float* arow = attn + ((long)h*L+l)*L + n*3;
    ar[h][n]=arow[0]+arow[1]+arow[2];
  }
  __syncthreads();
  int c=t&127, hg=(t>>7)*4;
  int rl=ridx[l];
  float scc=sc[c], bic=bi[c];
  float acc0=0,acc1=0,acc2=0,acc3=0;
  const float* zrow = z + ((long)rl*NRES)*CZ + c;
  const float* mr = murs + (long)rl*NRES*2;
  for(int n=0;n<NRES;n++){
    float zv=(zrow[(long)n*CZ] - mr[n*2])*mr[n*2+1]*scc + bic;
    acc0+=ar[hg+0][n]*zv; acc1+=ar[hg+1][n]*zv;
    acc2+=ar[hg+2][n]*zv; acc3+=ar[hg+3][n]*zv;
  }
  float* crow = cat + (long)l*1536;
  crow[(hg+0)*192+64+c]=acc0; crow[(hg+1)*192+64+c]=acc1;
  crow[(hg+2)*192+64+c]=acc2; crow[(hg+3)*192+64+c]=acc3;
}

// ---------------- kernel 8: final GEMM + bias, tiled ---------------
// C[32 l][32 c] per block; K=1536 in 24 chunks of 64. grid (36,8).
__global__ __launch_bounds__(256) void k_final(const float* cat, const float* wout, const float* bout, float* out){
  int l0 = blockIdx.x*32, c0 = blockIdx.y*32, t = threadIdx.x;
  __shared__ float a_s[64][33];
  __shared__ __align__(16) float w_s[64][36];
  int tr = t>>3, tc = t&7;       // 32 rows x 8 col-groups(4)
  float4 acc = {0,0,0,0};
  for(int kc=0; kc<24; kc++){
    int k0 = kc*64;
    {
      int row = t>>3, kk0 = (t&7)*8;
      const float4* src = (const float4*)(cat + (long)(l0+row)*1536 + k0 + kk0);
      float4 v0 = src[0], v1 = src[1];
      a_s[kk0+0][row]=v0.x; a_s[kk0+1][row]=v0.y; a_s[kk0+2][row]=v0.z; a_s[kk0+3][row]=v0.w;
      a_s[kk0+4][row]=v1.x; a_s[kk0+5][row]=v1.y; a_s[kk0+6][row]=v1.z; a_s[kk0+7][row]=v1.w;
    }
    #pragma unroll
    for(int kk2=0; kk2<2; kk2++){
      int kk = (t>>3) + 32*kk2;
      *(float4*)&w_s[kk][(t&7)*4] = *(const float4*)(wout + (long)(k0+kk)*256 + c0 + (t&7)*4);
    }
    __syncthreads();
    #pragma unroll 8
    for(int kk=0; kk<64; kk++){
      float a0 = a_s[kk][tr];
      float4 b4 = *(const float4*)&w_s[kk][tc*4];
      acc.x+=a0*b4.x; acc.y+=a0*b4.y; acc.z+=a0*b4.z; acc.w+=a0*b4.w;
    }
    __syncthreads();
  }
  float4 bv = *(const float4*)(bout + c0 + tc*4);
  acc.x+=bv.x; acc.y+=bv.y; acc.z+=bv.z; acc.w+=bv.w;
  *(float4*)(out + (long)(l0+tr)*256 + c0 + tc*4) = acc;
}

extern "C" void kernel_launch(void* const* d_in, const int* in_sizes, int n_in,
                              void* d_out, int out_size, void* d_ws, size_t ws_size,
                              hipStream_t stream) {
  const float* s      = (const float*)d_in[0];
  const float* z      = (const float*)d_in[1];
  const float* rot    = (const float*)d_in[2];
  const float* trans  = (const float*)d_in[3];
  const float* mask   = (const float*)d_in[4];
  const float* lnss   = (const float*)d_in[5];
  const float* lnsb   = (const float*)d_in[6];
  const float* lnzs   = (const float*)d_in[7];
  const float* lnzb   = (const float*)d_in[8];
  const float* wq     = (const float*)d_in[9];
  const float* wk     = (const float*)d_in[10];
  const float* wv     = (const float*)d_in[11];
  const float* wqp    = (const float*)d_in[12];
  const float* wkp    = (const float*)d_in[13];
  const float* wvp    = (const float*)d_in[14];
  const float* wb     = (const float*)d_in[15];
  const float* hws    = (const float*)d_in[16];
  const float* wout   = (const float*)d_in[17];
  const float* bout   = (const float*)d_in[18];
  const int*  ridx    = (const int*)d_in[19];

  float* ws  = (float*)d_ws;
  float* out = (float*)d_out;

  float* sln  = ws + OFF_SLN;
  float* proj = ws + OFF_PROJ;
  float* wpk  = ws + OFF_WPK;
  float* qcat = ws + OFF_QCAT;
  float* kcat = ws + OFF_KCAT;
  float* vcat = ws + OFF_VCAT;
  float* bres = ws + OFF_BRES;
  float* murs = ws + OFF_MURS;
  float* attn = ws + OFF_ATTN;
  float* cat  = ws + OFF_CAT;

  k_packw<<<dim3(256), dim3(256), 0, stream>>>(wq, wk, wv, wqp, wkp, wvp, wpk);
  k_ln_s<<<dim3(L), dim3(CS), 0, stream>>>(s, lnss, lnsb, sln);
  k_proj<<<dim3(18,17), dim3(256), 0, stream>>>(sln, wpk, proj);
  k_ln_z<<<dim3(NRES*NRES/32), dim3(256), 0, stream>>>(z, lnzs, lnzb, wb, murs, bres);
  k_rigid<<<dim3(L), dim3(256), 0, stream>>>(proj, rot, trans, mask, hws, qcat, kcat, vcat);
  k_scores<<<dim3(L/16, H), dim3(256), 0, stream>>>(qcat, kcat, bres, ridx, attn);
  k_av<<<dim3(L/32, H), dim3(256), 0, stream>>>(attn, vcat, rot, trans, cat);
  k_opair<<<dim3(L), dim3(256), 0, stream>>>(attn, z, murs, lnzs, lnzb, ridx, cat);
  k_final<<<dim3(36,8), dim3(256), 0, stream>>>(cat, wout, bout, out);
}